// Round 1
// baseline (1063.742 us; speedup 1.0000x reference)
//
#include <hip/hip_runtime.h>

// FrequencyAwareSpatialAttention: 3600 independent 17x17 windows.
// Per window: depthwise 3x3 sobel (pad=1, zero pad inside window),
// conv 64->16 3x3 (pad=1) + b1 + relu, conv 16->1 1x1 + b2, sigmoid,
// clip[0.05,0.95], scatter to [B,1,510,510].

#define WS 17
#define PS 19              // 17 + 2 zero-pad border
#define PSS (PS * PS)      // 361
#define CG 16              // channels per group
#define NG 4               // 4 groups -> 64 channels
#define NT 320             // 5 waves

__global__ __launch_bounds__(NT)
void fasa_kernel(const float* __restrict__ x,
                 const float* __restrict__ sobel_w,
                 const float* __restrict__ w1,
                 const float* __restrict__ b1,
                 const float* __restrict__ w2,
                 const float* __restrict__ b2,
                 float* __restrict__ out)
{
    __shared__ float xst[CG * PSS];   // padded x tile, 16 channels
    __shared__ float fr [CG * PSS];   // padded sobel output, 16 channels

    const int t   = threadIdx.x;
    const int win = blockIdx.x;       // b*900 + wh*30 + ww
    const int b   = win / 900;
    const int rem = win % 900;
    const int wh  = rem / 30;
    const int ww  = rem % 30;
    const int h0  = wh * WS;
    const int w0  = ww * WS;

    // zero both LDS buffers once; borders stay 0 across all groups
    for (int i = t; i < CG * PSS; i += NT) { xst[i] = 0.f; fr[i] = 0.f; }

    // conv1 accumulators: one output pixel per thread (t < 289)
    const bool hasPix = (t < WS * WS);
    const int pi = t / WS;
    const int pj = t % WS;
    float acc[16];
#pragma unroll
    for (int o = 0; o < 16; ++o) acc[o] = b1[o];

    // sobel work split: fixed channel per thread, strided pixels
    const int sc   = t % CG;          // local channel
    const int slot = t / CG;          // 0..19

    __syncthreads();

    for (int g = 0; g < NG; ++g) {
        // ---- stage x group into padded LDS interior ----
        const float* xg = x + (b * 64 + g * CG) * (510 * 510) + h0 * 510 + w0;
        for (int idx = t; idx < CG * WS * WS; idx += NT) {
            int c = idx / (WS * WS);
            int p = idx % (WS * WS);
            int i = p / WS, j = p % WS;
            xst[c * PSS + (i + 1) * PS + (j + 1)] =
                xg[c * (510 * 510) + i * 510 + j];
        }
        __syncthreads();

        // ---- depthwise sobel: xst -> fr ----
        {
            float sw[9];
            const float* swp = sobel_w + (g * CG + sc) * 9;
#pragma unroll
            for (int k = 0; k < 9; ++k) sw[k] = swp[k];
            for (int k = 0; k < 15; ++k) {
                int p = slot + 20 * k;
                if (p < WS * WS) {
                    int i = p / WS, j = p % WS;
                    // output (i,j) reads padded (i+di, j+dj), di,dj in 0..2
                    const float* src = xst + sc * PSS + i * PS + j;
                    float a = 0.f;
#pragma unroll
                    for (int di = 0; di < 3; ++di)
#pragma unroll
                        for (int dj = 0; dj < 3; ++dj)
                            a = fmaf(sw[di * 3 + dj], src[di * PS + dj], a);
                    fr[sc * PSS + (i + 1) * PS + (j + 1)] = a;
                }
            }
        }
        __syncthreads();

        // ---- conv1 partial accumulation over this channel group ----
        if (hasPix) {
            for (int c = 0; c < CG; ++c) {
                const float* fp = fr + c * PSS + pi * PS + pj;
                float f[9];
#pragma unroll
                for (int di = 0; di < 3; ++di)
#pragma unroll
                    for (int dj = 0; dj < 3; ++dj)
                        f[di * 3 + dj] = fp[di * PS + dj];
                const float* wp = w1 + (g * CG + c) * 9;  // + o*(64*9) + k
#pragma unroll
                for (int o = 0; o < 16; ++o) {
#pragma unroll
                    for (int k = 0; k < 9; ++k)
                        acc[o] = fmaf(wp[o * (64 * 9) + k], f[k], acc[o]);
                }
            }
        }
        __syncthreads();
    }

    // ---- relu + 1x1 conv + sigmoid + clip + scatter ----
    if (hasPix) {
        float pre = b2[0];
#pragma unroll
        for (int o = 0; o < 16; ++o)
            pre = fmaf(w2[o], fmaxf(acc[o], 0.f), pre);
        float s = 1.f / (1.f + __expf(-pre));
        s = fminf(fmaxf(s, 0.05f), 0.95f);
        out[(b * 510 + (h0 + pi)) * 510 + (w0 + pj)] = s;
    }
}

extern "C" void kernel_launch(void* const* d_in, const int* in_sizes, int n_in,
                              void* d_out, int out_size, void* d_ws, size_t ws_size,
                              hipStream_t stream) {
    const float* x       = (const float*)d_in[0];
    const float* sobel_w = (const float*)d_in[1];
    const float* w1      = (const float*)d_in[2];
    const float* b1      = (const float*)d_in[3];
    const float* w2      = (const float*)d_in[4];
    const float* b2      = (const float*)d_in[5];
    float* out = (float*)d_out;

    dim3 grid(3600);
    dim3 block(NT);
    fasa_kernel<<<grid, block, 0, stream>>>(x, sobel_w, w1, b1, w2, b2, out);
}

// Round 2
// 216.222 us; speedup vs baseline: 4.9197x; 4.9197x over previous
//
#include <hip/hip_runtime.h>

// FrequencyAwareSpatialAttention via MFMA.
// 3600 windows of 17x17. Per window:
//   depthwise 3x3 sobel (zero-pad inside window)  -> freq (bf16, LDS, [pixel][channel])
//   conv 64->16 3x3 (pad 1): 9 offsets x (16x16x32 bf16 mfma over K=64 channels)
//   + b1, relu, 1x1 conv 16->1 + b2, sigmoid, clip, scatter.

#define WSZ 17
#define PS  19            // padded 17+2
#define PSS (PS * PS)     // 361

typedef __attribute__((ext_vector_type(8))) short bf16x8;
typedef __attribute__((ext_vector_type(4))) float f32x4;

// XOR swizzle: involution within each 128B freq row (row = padded pixel).
__device__ __forceinline__ int swz(int off) {
    return off ^ (((off >> 7) & 7) << 4);
}

__device__ __forceinline__ unsigned short f2bf(float f) {
    union { float f; unsigned u; } v; v.f = f;
    unsigned u = v.u;
    unsigned r = u + 0x7fffu + ((u >> 16) & 1u);   // RNE
    return (unsigned short)(r >> 16);
}

// Pre-kernel: transpose+convert w1 [16][64][3][3] fp32 into A-fragment order.
// Fragment (dij, ks): lane l holds A[m = l&15][k = ks*32 + 8*(l>>4) + j], j=0..7.
// Stored at wt + (dij*2+ks)*1024 + l*16 bytes.
__global__ void prep_w1(const float* __restrict__ w1, unsigned short* __restrict__ wt) {
    const int dij = blockIdx.x >> 1;
    const int ks  = blockIdx.x & 1;
    const int l   = threadIdx.x;           // 0..63
    const int m   = l & 15;
    const int kb  = ks * 32 + 8 * (l >> 4);
    bf16x8 v;
#pragma unroll
    for (int j = 0; j < 8; ++j)
        v[j] = (short)f2bf(w1[m * 576 + (kb + j) * 9 + dij]);
    ((bf16x8*)wt)[blockIdx.x * 64 + l] = v;
}

__global__ __launch_bounds__(256)
void fasa_mfma(const float* __restrict__ x,
               const float* __restrict__ sobel_w,
               const unsigned short* __restrict__ wt,
               const float* __restrict__ b1,
               const float* __restrict__ w2,
               const float* __restrict__ b2,
               float* __restrict__ out)
{
    __shared__ float xst[16 * PSS];                    // 23.1 KB, one 16-ch group
    __shared__ __align__(16) char frq[PSS * 128];      // 46.2 KB, [pp][c] bf16 swizzled

    const int t    = threadIdx.x;
    const int lane = t & 63;
    const int wave = t >> 6;

    const int win = blockIdx.x;                        // b*900 + wh*30 + ww
    const int b   = win / 900;
    const int rem = win % 900;
    const int h0  = (rem / 30) * WSZ;
    const int w0  = (rem % 30) * WSZ;

    // zero LDS (borders of both buffers must be 0; interiors get overwritten)
    for (int i = t; i < 16 * PSS / 4; i += 256)
        ((f32x4*)xst)[i] = (f32x4){0.f, 0.f, 0.f, 0.f};
    for (int i = t; i < PSS * 128 / 16; i += 256)
        ((f32x4*)frq)[i] = (f32x4){0.f, 0.f, 0.f, 0.f};
    __syncthreads();

    const int cpair = t & 7;       // channel pair within 16-ch group
    const int slot  = t >> 3;      // 0..31

    for (int g = 0; g < 4; ++g) {
        const float* xg = x + ((size_t)(b * 64 + g * 16)) * (510 * 510)
                            + h0 * 510 + w0;
        // ---- stage x group (fp32) into padded xst interior ----
        for (int idx = t; idx < 16 * 289; idx += 256) {
            int c = idx / 289;
            int p = idx - c * 289;
            int pi = p / 17, pj = p - pi * 17;
            xst[c * PSS + (pi + 1) * PS + (pj + 1)] =
                xg[c * (510 * 510) + pi * 510 + pj];
        }
        __syncthreads();

        // ---- sobel: two channels per thread, pack 2 bf16 -> u32 ds_write ----
        {
            const int c0 = 2 * cpair;                      // local channel
            const int cg = g * 16 + c0;                    // global channel
            const float* s0 = sobel_w + (size_t)cg * 9;
            float sw0[9], sw1[9];
#pragma unroll
            for (int k = 0; k < 9; ++k) { sw0[k] = s0[k]; sw1[k] = s0[9 + k]; }
            for (int k = 0; k < 10; ++k) {
                int p = slot + 32 * k;
                if (p < 289) {
                    int pi = p / 17, pj = p - pi * 17;
                    const float* a0 = xst + c0 * PSS + pi * PS + pj;
                    const float* a1 = a0 + PSS;
                    float f0 = 0.f, f1 = 0.f;
#pragma unroll
                    for (int di = 0; di < 3; ++di)
#pragma unroll
                        for (int dj = 0; dj < 3; ++dj) {
                            f0 = fmaf(sw0[di * 3 + dj], a0[di * PS + dj], f0);
                            f1 = fmaf(sw1[di * 3 + dj], a1[di * PS + dj], f1);
                        }
                    int pp = (pi + 1) * PS + (pj + 1);
                    unsigned val = (unsigned)f2bf(f0) | ((unsigned)f2bf(f1) << 16);
                    *(unsigned*)(frq + swz(pp * 128 + cg * 2)) = val;
                }
            }
        }
        __syncthreads();
    }

    // ---- conv1 via MFMA: per wave, N-tiles {wave, wave+4, ...} of 16 pixels ----
    bf16x8 wf[18];
#pragma unroll
    for (int i = 0; i < 18; ++i)
        wf[i] = ((const bf16x8*)wt)[i * 64 + lane];

    float b1v[4], w2v[4];
#pragma unroll
    for (int r = 0; r < 4; ++r) {
        int m = 4 * (lane >> 4) + r;
        b1v[r] = b1[m];
        w2v[r] = w2[m];
    }
    const float b2v = b2[0];

    const int n   = lane & 15;          // pixel within tile (MFMA N / out column)
    const int g16 = (lane >> 4) * 16;   // byte offset of this lane's 8-channel chunk
    const int DOFF[9] = {0, 1, 2, PS, PS + 1, PS + 2, 2 * PS, 2 * PS + 1, 2 * PS + 2};

    for (int nt = wave; nt < 19; nt += 4) {
        int p  = nt * 16 + n;
        int pv = p > 288 ? 288 : p;     // clamp dead lanes of last tile
        int pi = pv / 17, pj = pv - pi * 17;
        int base = (pi * PS + pj) * 128 + g16;   // pp for (di,dj)=(0,0) is pi*19+pj

        f32x4 acc = {0.f, 0.f, 0.f, 0.f};
#pragma unroll
        for (int d = 0; d < 9; ++d) {
            int off = base + DOFF[d] * 128;
            bf16x8 bfA = *(const bf16x8*)(frq + swz(off));
            bf16x8 bfB = *(const bf16x8*)(frq + swz(off + 64));
            acc = __builtin_amdgcn_mfma_f32_16x16x32_bf16(wf[2 * d],     bfA, acc, 0, 0, 0);
            acc = __builtin_amdgcn_mfma_f32_16x16x32_bf16(wf[2 * d + 1], bfB, acc, 0, 0, 0);
        }

        // epilogue: +b1, relu, dot with w2 (rows split across lane>>4 groups)
        float part = 0.f;
#pragma unroll
        for (int r = 0; r < 4; ++r) {
            float h = acc[r] + b1v[r];
            part = fmaf(w2v[r], fmaxf(h, 0.f), part);
        }
        part += __shfl_xor(part, 16);
        part += __shfl_xor(part, 32);

        if (lane < 16 && p < 289) {
            float pre = part + b2v;
            float s = 1.f / (1.f + expf(-pre));
            s = fminf(fmaxf(s, 0.05f), 0.95f);
            out[((size_t)(b * 510 + h0 + pi)) * 510 + (w0 + pj)] = s;
        }
    }
}

extern "C" void kernel_launch(void* const* d_in, const int* in_sizes, int n_in,
                              void* d_out, int out_size, void* d_ws, size_t ws_size,
                              hipStream_t stream) {
    const float* x       = (const float*)d_in[0];
    const float* sobel_w = (const float*)d_in[1];
    const float* w1      = (const float*)d_in[2];
    const float* b1      = (const float*)d_in[3];
    const float* w2      = (const float*)d_in[4];
    const float* b2      = (const float*)d_in[5];
    float* out = (float*)d_out;
    unsigned short* wtab = (unsigned short*)d_ws;   // 18*64*16 = 18432 B

    prep_w1<<<dim3(18), dim3(64), 0, stream>>>(w1, wtab);
    fasa_mfma<<<dim3(3600), dim3(256), 0, stream>>>(x, sobel_w, wtab, b1, w2, b2, out);
}

// Round 3
// 203.632 us; speedup vs baseline: 5.2238x; 1.0618x over previous
//
#include <hip/hip_runtime.h>

// FrequencyAwareSpatialAttention via MFMA, register-resident sobel.
// 3600 windows of 17x17. Per window-block:
//   stage+sobel: each task (row, ch-pair) loads 3 input rows from global into
//   regs, 9-tap sobel in regs, packs bf16x2, writes frq[pp][c] LDS row.
//   conv 64->16 3x3 (pad 1): 9 offsets x 2 (16x16x32 bf16 mfma), K=64 channels
//   + b1, relu, 1x1 conv 16->1 + b2, sigmoid, clip, scatter.

#define WSZ 17
#define PS  19            // padded 17+2
#define PSS (PS * PS)     // 361
#define NT  320           // 5 waves

typedef __attribute__((ext_vector_type(8))) short bf16x8;
typedef __attribute__((ext_vector_type(4))) float f32x4;

// XOR swizzle: involution within each 128B frq row (row = padded pixel).
__device__ __forceinline__ int swz(int off) {
    return off ^ (((off >> 7) & 7) << 4);
}

__device__ __forceinline__ unsigned short f2bf(float f) {
    union { float f; unsigned u; } v; v.f = f;
    unsigned u = v.u;
    unsigned r = u + 0x7fffu + ((u >> 16) & 1u);   // RNE
    return (unsigned short)(r >> 16);
}

// Pre-kernel: transpose+convert w1 [16][64][3][3] fp32 into A-fragment order.
// Fragment (dij, ks): lane l holds A[m = l&15][k = ks*32 + 8*(l>>4) + j], j=0..7.
__global__ void prep_w1(const float* __restrict__ w1, unsigned short* __restrict__ wt) {
    const int dij = blockIdx.x >> 1;
    const int ks  = blockIdx.x & 1;
    const int l   = threadIdx.x;           // 0..63
    const int m   = l & 15;
    const int kb  = ks * 32 + 8 * (l >> 4);
    bf16x8 v;
#pragma unroll
    for (int j = 0; j < 8; ++j)
        v[j] = (short)f2bf(w1[m * 576 + (kb + j) * 9 + dij]);
    ((bf16x8*)wt)[blockIdx.x * 64 + l] = v;
}

__global__ __launch_bounds__(NT)
void fasa_mfma(const float* __restrict__ x,
               const float* __restrict__ sobel_w,
               const unsigned short* __restrict__ wt,
               const float* __restrict__ b1,
               const float* __restrict__ w2,
               const float* __restrict__ b2,
               float* __restrict__ out)
{
    __shared__ __align__(16) char frq[PSS * 128];   // 46.2 KB, [pp][c] bf16 swizzled

    const int t    = threadIdx.x;
    const int lane = t & 63;
    const int wave = t >> 6;

    const int win = blockIdx.x;                     // b*900 + wh*30 + ww
    const int b   = win / 900;
    const int rem = win % 900;
    const int h0  = (rem / 30) * WSZ;
    const int w0  = (rem % 30) * WSZ;

    // ---- zero the 72 border rows of frq (interior rows all get written) ----
    // one f32x4 per (row, k) unit so consecutive lanes hit distinct banks
    for (int u = t; u < 72 * 8; u += NT) {
        int r = u >> 3, k = u & 7;
        int row;
        if      (r < 19) row = r;                   // pi == 0
        else if (r < 38) row = 342 + (r - 19);      // pi == 18
        else if (r < 55) row = (r - 37) * PS;       // pj == 0, pi 1..17
        else             row = (r - 54) * PS + 18;  // pj == 18, pi 1..17
        *(f32x4*)(frq + row * 128 + k * 16) = (f32x4){0.f, 0.f, 0.f, 0.f};
    }
    // no barrier here: border rows and interior rows are disjoint addresses;
    // the single barrier before the MFMA phase orders everything.

    // ---- stage + sobel: 544 tasks = (row i 0..16) x (channel pair cp 0..31) ----
#pragma unroll 1
    for (int q = t; q < 544; q += NT) {
        const int cp = q & 31;
        const int i  = q >> 5;
        unsigned pk[17];
#pragma unroll
        for (int cc = 0; cc < 2; ++cc) {
            const int c = 2 * cp + cc;
            const float* xc = x + ((size_t)(b * 64 + c)) * (510 * 510)
                                + (size_t)h0 * 510 + w0;
            float r[3][19];   // window-local zero pad at [*][0] and [*][18]
#pragma unroll
            for (int dr = 0; dr < 3; ++dr) {
                const int ir = i + dr - 1;
                r[dr][0] = 0.f; r[dr][18] = 0.f;
                if (ir >= 0 && ir < 17) {
                    const float* p = xc + ir * 510;
#pragma unroll
                    for (int k4 = 0; k4 < 4; ++k4) {
                        f32x4 v;
                        __builtin_memcpy(&v, p + 4 * k4, 16);
#pragma unroll
                        for (int e = 0; e < 4; ++e) r[dr][1 + 4 * k4 + e] = v[e];
                    }
                    r[dr][17] = p[16];
                } else {
#pragma unroll
                    for (int k = 1; k < 18; ++k) r[dr][k] = 0.f;
                }
            }
            float sw[9];
#pragma unroll
            for (int k = 0; k < 9; ++k) sw[k] = sobel_w[c * 9 + k];
#pragma unroll
            for (int j = 0; j < 17; ++j) {
                float a = 0.f;
#pragma unroll
                for (int dr = 0; dr < 3; ++dr)
#pragma unroll
                    for (int dj = 0; dj < 3; ++dj)
                        a = fmaf(sw[dr * 3 + dj], r[dr][j + dj], a);
                unsigned short hh = f2bf(a);
                if (cc == 0) pk[j] = hh;
                else         pk[j] |= ((unsigned)hh) << 16;
            }
        }
        const int ppb = (i + 1) * PS + 1;
#pragma unroll
        for (int j = 0; j < 17; ++j)
            *(unsigned*)(frq + swz((ppb + j) * 128 + cp * 4)) = pk[j];
    }

    // ---- W fragments + epilogue constants: issue before barrier (latency hides) ----
    bf16x8 wf[18];
#pragma unroll
    for (int i = 0; i < 18; ++i)
        wf[i] = ((const bf16x8*)wt)[i * 64 + lane];

    float b1v[4], w2v[4];
#pragma unroll
    for (int r = 0; r < 4; ++r) {
        int m = 4 * (lane >> 4) + r;
        b1v[r] = b1[m];
        w2v[r] = w2[m];
    }
    const float b2v = b2[0];

    __syncthreads();

    // ---- conv1 via MFMA: wave w handles pixel tiles {w, w+5, w+10, w+15} ----
    const int n   = lane & 15;          // pixel within tile (MFMA N)
    const int g16 = (lane >> 4) * 16;   // 8-channel chunk byte offset
    const int DOFF[9] = {0, 1, 2, PS, PS + 1, PS + 2, 2 * PS, 2 * PS + 1, 2 * PS + 2};

#pragma unroll 1
    for (int nt = wave; nt < 19; nt += 5) {
        int p  = nt * 16 + n;
        int pv = p > 288 ? 288 : p;     // clamp dead lanes of last tile
        int pi = pv / 17, pj = pv - pi * 17;
        int base = (pi * PS + pj) * 128 + g16;

        f32x4 acc = {0.f, 0.f, 0.f, 0.f};
#pragma unroll
        for (int d = 0; d < 9; ++d) {
            int off = base + DOFF[d] * 128;
            bf16x8 bfA = *(const bf16x8*)(frq + swz(off));
            bf16x8 bfB = *(const bf16x8*)(frq + swz(off + 64));
            acc = __builtin_amdgcn_mfma_f32_16x16x32_bf16(wf[2 * d],     bfA, acc, 0, 0, 0);
            acc = __builtin_amdgcn_mfma_f32_16x16x32_bf16(wf[2 * d + 1], bfB, acc, 0, 0, 0);
        }

        float part = 0.f;
#pragma unroll
        for (int r = 0; r < 4; ++r)
            part = fmaf(w2v[r], fmaxf(acc[r] + b1v[r], 0.f), part);
        part += __shfl_xor(part, 16);
        part += __shfl_xor(part, 32);

        if (lane < 16 && p < 289) {
            float pre = part + b2v;
            float s = 1.f / (1.f + expf(-pre));
            s = fminf(fmaxf(s, 0.05f), 0.95f);
            out[((size_t)(b * 510 + h0 + pi)) * 510 + (w0 + pj)] = s;
        }
    }
}

extern "C" void kernel_launch(void* const* d_in, const int* in_sizes, int n_in,
                              void* d_out, int out_size, void* d_ws, size_t ws_size,
                              hipStream_t stream) {
    const float* x       = (const float*)d_in[0];
    const float* sobel_w = (const float*)d_in[1];
    const float* w1      = (const float*)d_in[2];
    const float* b1      = (const float*)d_in[3];
    const float* w2      = (const float*)d_in[4];
    const float* b2      = (const float*)d_in[5];
    float* out = (float*)d_out;
    unsigned short* wtab = (unsigned short*)d_ws;   // 18*64*16 = 18432 B

    prep_w1<<<dim3(18), dim3(64), 0, stream>>>(w1, wtab);
    fasa_mfma<<<dim3(3600), dim3(NT), 0, stream>>>(x, sobel_w, wtab, b1, w2, b2, out);
}

// Round 4
// 137.044 us; speedup vs baseline: 7.7620x; 1.4859x over previous
//
#include <hip/hip_runtime.h>

// FrequencyAwareSpatialAttention via MFMA, column-per-lane coalesced sobel.
// 3600 windows of 17x17. Per block (one window):
//   staging: lane = (channel_half, column j); loads its 17-px column with
//   coalesced wave access (lanes j=0..16 consecutive), sobel via vertical
//   partials in regs + __shfl(lane+/-1) horizontal combine, bf16 pack via
//   __shfl_xor(32), write frq[pp][c] (swizzled).
//   conv 64->16 3x3 (pad 1): 9 offsets x 2 mfma_f32_16x16x32_bf16, K=64
//   + b1, relu, 1x1 conv 16->1 + b2, sigmoid, clip, scatter.

#define WSZ 17
#define PS  19            // padded 17+2
#define PSS (PS * PS)     // 361
#define NT  256           // 4 waves

typedef __attribute__((ext_vector_type(8))) short bf16x8;
typedef __attribute__((ext_vector_type(4))) float f32x4;

// XOR swizzle: involution within each 128B frq row (row = padded pixel).
__device__ __forceinline__ int swz(int off) {
    return off ^ (((off >> 7) & 7) << 4);
}

__device__ __forceinline__ unsigned short f2bf(float f) {
    union { float f; unsigned u; } v; v.f = f;
    unsigned u = v.u;
    unsigned r = u + 0x7fffu + ((u >> 16) & 1u);   // RNE
    return (unsigned short)(r >> 16);
}

// Pre-kernel: transpose+convert w1 [16][64][3][3] fp32 into A-fragment order.
// Fragment (dij, ks): lane l holds A[m = l&15][k = ks*32 + 8*(l>>4) + j], j=0..7.
__global__ void prep_w1(const float* __restrict__ w1, unsigned short* __restrict__ wt) {
    const int dij = blockIdx.x >> 1;
    const int ks  = blockIdx.x & 1;
    const int l   = threadIdx.x;           // 0..63
    const int m   = l & 15;
    const int kb  = ks * 32 + 8 * (l >> 4);
    bf16x8 v;
#pragma unroll
    for (int j = 0; j < 8; ++j)
        v[j] = (short)f2bf(w1[m * 576 + (kb + j) * 9 + dij]);
    ((bf16x8*)wt)[blockIdx.x * 64 + l] = v;
}

__global__ __launch_bounds__(NT)
void fasa_mfma(const float* __restrict__ x,
               const float* __restrict__ sobel_w,
               const unsigned short* __restrict__ wt,
               const float* __restrict__ b1,
               const float* __restrict__ w2,
               const float* __restrict__ b2,
               float* __restrict__ out)
{
    __shared__ __align__(16) char frq[PSS * 128];   // 46.2 KB, [pp][c] bf16 swizzled

    const int t    = threadIdx.x;
    const int lane = t & 63;
    const int wave = t >> 6;

    const int win = blockIdx.x;                     // b*900 + wh*30 + ww
    const int b   = win / 900;
    const int rem = win % 900;
    const int h0  = (rem / 30) * WSZ;
    const int w0  = (rem % 30) * WSZ;

    // ---- zero the 72 border rows of frq (interior rows all get written) ----
    for (int u = t; u < 72 * 8; u += NT) {
        int r = u >> 3, k = u & 7;
        int row;
        if      (r < 19) row = r;                   // pi == 0
        else if (r < 38) row = 342 + (r - 19);      // pi == 18
        else if (r < 55) row = (r - 37) * PS;       // pj == 0, pi 1..17
        else             row = (r - 54) * PS + 18;  // pj == 18, pi 1..17
        *(f32x4*)(frq + row * 128 + k * 16) = (f32x4){0.f, 0.f, 0.f, 0.f};
    }

    // ---- staging + sobel: lane = (csub, j); 8 channel-pair tasks per wave ----
    const int j    = lane & 31;      // column within window, active when j<17
    const int csub = lane >> 5;      // which channel of the pair
    const bool jac = (j < 17);

#pragma unroll 1
    for (int it = 0; it < 8; ++it) {
        const int task = wave * 8 + it;        // 0..31 channel pairs
        const int c    = 2 * task + csub;      // channel 0..63

        // sobel weights for this channel (wave-half-uniform address)
        float sw[9];
        {
            const float* swp = sobel_w + c * 9;
            f32x4 a, bb;
            __builtin_memcpy(&a,  swp,     16);
            __builtin_memcpy(&bb, swp + 4, 16);
            sw[0]=a[0]; sw[1]=a[1]; sw[2]=a[2]; sw[3]=a[3];
            sw[4]=bb[0]; sw[5]=bb[1]; sw[6]=bb[2]; sw[7]=bb[3];
            sw[8]=swp[8];
        }

        // load column j of this channel's window (coalesced across lanes)
        float xr[19];                          // i-padded column
        xr[0] = 0.f; xr[18] = 0.f;
        if (jac) {
            const float* xc = x + ((size_t)(b * 64 + c)) * (510 * 510)
                                + (size_t)h0 * 510 + (w0 + j);
#pragma unroll
            for (int i = 0; i < 17; ++i) xr[i + 1] = xc[i * 510];
        } else {
#pragma unroll
            for (int i = 0; i < 17; ++i) xr[i + 1] = 0.f;
        }

        // sobel: vertical partials per dj, horizontal combine via shfl.
        // out[i][j] = p1(j) + p0(j-1) + p2(j+1); lanes j>=17 hold zeros so
        // shfl wraparound at group edges naturally supplies the zero pad.
        unsigned pk[17];
#pragma unroll
        for (int i = 0; i < 17; ++i) {
            float p0 = fmaf(sw[0], xr[i], fmaf(sw[3], xr[i+1], sw[6] * xr[i+2]));
            float p1 = fmaf(sw[1], xr[i], fmaf(sw[4], xr[i+1], sw[7] * xr[i+2]));
            float p2 = fmaf(sw[2], xr[i], fmaf(sw[5], xr[i+1], sw[8] * xr[i+2]));
            float o  = p1 + __shfl(p0, lane - 1) + __shfl(p2, lane + 1);
            unsigned hv = f2bf(o);
            unsigned ov = (unsigned)__shfl_xor((int)hv, 32);
            pk[i] = hv | (ov << 16);           // lo = ch 2*task, hi = ch 2*task+1
        }

        if (csub == 0 && jac) {
#pragma unroll
            for (int i = 0; i < 17; ++i)
                *(unsigned*)(frq + swz(((i + 1) * PS + (j + 1)) * 128 + task * 4)) = pk[i];
        }
    }

    // ---- W fragments + epilogue constants: issue before barrier ----
    bf16x8 wf[18];
#pragma unroll
    for (int i = 0; i < 18; ++i)
        wf[i] = ((const bf16x8*)wt)[i * 64 + lane];

    float b1v[4], w2v[4];
#pragma unroll
    for (int r = 0; r < 4; ++r) {
        int m = 4 * (lane >> 4) + r;
        b1v[r] = b1[m];
        w2v[r] = w2[m];
    }
    const float b2v = b2[0];

    __syncthreads();

    // ---- conv1 via MFMA: wave w handles pixel tiles {w, w+4, w+8, ...} ----
    const int n   = lane & 15;          // pixel within tile (MFMA N)
    const int g16 = (lane >> 4) * 16;   // 8-channel chunk byte offset
    const int DOFF[9] = {0, 1, 2, PS, PS + 1, PS + 2, 2 * PS, 2 * PS + 1, 2 * PS + 2};

#pragma unroll 1
    for (int nt = wave; nt < 19; nt += 4) {
        int p  = nt * 16 + n;
        int pv = p > 288 ? 288 : p;     // clamp dead lanes of last tile
        int pi = pv / 17, pj = pv - pi * 17;
        int base = (pi * PS + pj) * 128 + g16;

        f32x4 acc = {0.f, 0.f, 0.f, 0.f};
#pragma unroll
        for (int d = 0; d < 9; ++d) {
            int off = base + DOFF[d] * 128;
            bf16x8 bfA = *(const bf16x8*)(frq + swz(off));
            bf16x8 bfB = *(const bf16x8*)(frq + swz(off + 64));
            acc = __builtin_amdgcn_mfma_f32_16x16x32_bf16(wf[2 * d],     bfA, acc, 0, 0, 0);
            acc = __builtin_amdgcn_mfma_f32_16x16x32_bf16(wf[2 * d + 1], bfB, acc, 0, 0, 0);
        }

        float part = 0.f;
#pragma unroll
        for (int r = 0; r < 4; ++r)
            part = fmaf(w2v[r], fmaxf(acc[r] + b1v[r], 0.f), part);
        part += __shfl_xor(part, 16);
        part += __shfl_xor(part, 32);

        if (lane < 16 && p < 289) {
            float pre = part + b2v;
            float s = 1.f / (1.f + expf(-pre));
            s = fminf(fmaxf(s, 0.05f), 0.95f);
            out[((size_t)(b * 510 + h0 + pi)) * 510 + (w0 + pj)] = s;
        }
    }
}

extern "C" void kernel_launch(void* const* d_in, const int* in_sizes, int n_in,
                              void* d_out, int out_size, void* d_ws, size_t ws_size,
                              hipStream_t stream) {
    const float* x       = (const float*)d_in[0];
    const float* sobel_w = (const float*)d_in[1];
    const float* w1      = (const float*)d_in[2];
    const float* b1      = (const float*)d_in[3];
    const float* w2      = (const float*)d_in[4];
    const float* b2      = (const float*)d_in[5];
    float* out = (float*)d_out;
    unsigned short* wtab = (unsigned short*)d_ws;   // 18*64*16 = 18432 B

    prep_w1<<<dim3(18), dim3(64), 0, stream>>>(w1, wtab);
    fasa_mfma<<<dim3(3600), dim3(NT), 0, stream>>>(x, sobel_w, wtab, b1, w2, b2, out);
}

// Round 5
// 128.541 us; speedup vs baseline: 8.2755x; 1.0662x over previous
//
#include <hip/hip_runtime.h>

// FrequencyAwareSpatialAttention via MFMA, packed-fp32 sobel.
// Per block (one 17x17 window):
//   staging: lane = (pair_group, column j); loads both channels of a pair as
//   float2 columns (scalar-base + 32-bit voffset addressing), packed sobel
//   (v_pk_fma_f32), horizontal combine via ds_bpermute(lane+/-1), pack via
//   v_cvt_pk_bf16_f32, write frq[pp][c] (swizzled). A/B double-buffered loads.
//   conv 64->16 3x3 (pad 1): 9 offsets x 2 mfma_f32_16x16x32_bf16, K=64
//   + b1, relu, 1x1 conv 16->1 + b2, sigmoid, clip, scatter.

#define WSZ 17
#define PS  19            // padded 17+2
#define PSS (PS * PS)     // 361
#define NT  256           // 4 waves
#define CH  (510 * 510)   // floats per channel plane

typedef __attribute__((ext_vector_type(8))) short bf16x8;
typedef __attribute__((ext_vector_type(4))) float f32x4;
typedef __attribute__((ext_vector_type(2))) float f32x2;

// XOR swizzle: involution within each 128B frq row (row = padded pixel).
__device__ __forceinline__ int swz(int off) {
    return off ^ (((off >> 7) & 7) << 4);
}

__device__ __forceinline__ unsigned short f2bf(float f) {
    union { float f; unsigned u; } v; v.f = f;
    unsigned u = v.u;
    unsigned r = u + 0x7fffu + ((u >> 16) & 1u);   // RNE
    return (unsigned short)(r >> 16);
}

// Pre-kernel: transpose+convert w1 [16][64][3][3] fp32 into A-fragment order.
// Fragment (dij, ks): lane l holds A[m = l&15][k = ks*32 + 8*(l>>4) + j], j=0..7.
__global__ void prep_w1(const float* __restrict__ w1, unsigned short* __restrict__ wt) {
    const int dij = blockIdx.x >> 1;
    const int ks  = blockIdx.x & 1;
    const int l   = threadIdx.x;           // 0..63
    const int m   = l & 15;
    const int kb  = ks * 32 + 8 * (l >> 4);
    bf16x8 v;
#pragma unroll
    for (int jj = 0; jj < 8; ++jj)
        v[jj] = (short)f2bf(w1[m * 576 + (kb + jj) * 9 + dij]);
    ((bf16x8*)wt)[blockIdx.x * 64 + l] = v;
}

__global__ __launch_bounds__(NT, 3)
void fasa_mfma(const float* __restrict__ x,
               const float* __restrict__ sobel_w,
               const unsigned short* __restrict__ wt,
               const float* __restrict__ b1,
               const float* __restrict__ w2,
               const float* __restrict__ b2,
               float* __restrict__ out)
{
    __shared__ __align__(16) char frq[PSS * 128];   // 46.2 KB, [pp][c] bf16 swizzled

    const int t    = threadIdx.x;
    const int lane = t & 63;
    const int wave = __builtin_amdgcn_readfirstlane(t >> 6);

    const int win = blockIdx.x;                     // b*900 + wh*30 + ww
    const int b   = win / 900;
    const int rem = win % 900;
    const int h0  = (rem / 30) * WSZ;
    const int w0  = (rem % 30) * WSZ;

    // ---- zero the 72 border rows of frq (interior rows all get written) ----
    for (int u = t; u < 72 * 8; u += NT) {
        int r = u >> 3, k = u & 7;
        int row;
        if      (r < 19) row = r;                   // pi == 0
        else if (r < 38) row = 342 + (r - 19);      // pi == 18
        else if (r < 55) row = (r - 37) * PS;       // pj == 0, pi 1..17
        else             row = (r - 54) * PS + 18;  // pj == 18, pi 1..17
        *(f32x4*)(frq + row * 128 + k * 16) = (f32x4){0.f, 0.f, 0.f, 0.f};
    }

    // ---- staging: lane = (grp, j); pair(q) = wave*2 + grp + 8q, q = 0..3 ----
    const int j   = lane & 31;       // column, active when j < 17
    const int grp = lane >> 5;       // which pair of this wave's two
    const bool jac = (j < 17);
    const int bpm = ((lane - 1) & 63) << 2;   // bpermute byte addr, left
    const int bpp = ((lane + 1) & 63) << 2;   // bpermute byte addr, right

    // wave-uniform base (channel 4*wave); per-lane 32-bit byte offsets
    const float* xbase = x + ((size_t)(b * 64 + 4 * wave)) * CH
                           + (size_t)h0 * 510 + w0;
    const unsigned voffx = (unsigned)((grp * 2 * CH + j) * 4);
    const unsigned voffy = voffx + (unsigned)(CH * 4);

    auto LOADCOL = [&](f32x2* xr, int q) {
        const char* bp = (const char*)(xbase + (size_t)q * 16 * CH);
        xr[0] = (f32x2){0.f, 0.f}; xr[18] = (f32x2){0.f, 0.f};
        if (jac) {
#pragma unroll
            for (int i = 0; i < 17; ++i) {
                xr[i + 1].x = *(const float*)(bp + (voffx + (unsigned)i * 2040u));
                xr[i + 1].y = *(const float*)(bp + (voffy + (unsigned)i * 2040u));
            }
        } else {
#pragma unroll
            for (int i = 0; i < 17; ++i) xr[i + 1] = (f32x2){0.f, 0.f};
        }
    };

    auto DOSOBEL = [&](const f32x2* xr, int q) {
        const int c0 = 4 * wave + 2 * grp + 16 * q;   // first channel of pair
        f32x2 sw[9];
#pragma unroll
        for (int k = 0; k < 9; ++k) {
            sw[k].x = sobel_w[c0 * 9 + k];
            sw[k].y = sobel_w[(c0 + 1) * 9 + k];
        }
        const int pairOff = (c0 >> 1) * 4;            // pair byte offset in frq row
#pragma unroll
        for (int i = 0; i < 17; ++i) {
            f32x2 p0 = __builtin_elementwise_fma(sw[0], xr[i],
                         __builtin_elementwise_fma(sw[3], xr[i + 1], sw[6] * xr[i + 2]));
            f32x2 p1 = __builtin_elementwise_fma(sw[1], xr[i],
                         __builtin_elementwise_fma(sw[4], xr[i + 1], sw[7] * xr[i + 2]));
            f32x2 p2 = __builtin_elementwise_fma(sw[2], xr[i],
                         __builtin_elementwise_fma(sw[5], xr[i + 1], sw[8] * xr[i + 2]));
            // o(j) = p0(j-1) + p1(j) + p2(j+1); zero columns at j>=17 supply pads
            union { f32x2 f; int w[2]; } u0, u2, r0, r2;
            u0.f = p0; u2.f = p2;
            r0.w[0] = __builtin_amdgcn_ds_bpermute(bpm, u0.w[0]);
            r0.w[1] = __builtin_amdgcn_ds_bpermute(bpm, u0.w[1]);
            r2.w[0] = __builtin_amdgcn_ds_bpermute(bpp, u2.w[0]);
            r2.w[1] = __builtin_amdgcn_ds_bpermute(bpp, u2.w[1]);
            f32x2 o = p1 + r0.f + r2.f;
            unsigned pkv;
            asm("v_cvt_pk_bf16_f32 %0, %1, %2" : "=v"(pkv) : "v"(o.x), "v"(o.y));
            if (jac)
                *(unsigned*)(frq + swz(((i + 1) * PS + (j + 1)) * 128 + pairOff)) = pkv;
        }
    };

    // A/B double-buffered: loads of next pair overlap sobel of current
    f32x2 A[19], B[19];
    LOADCOL(A, 0);
    LOADCOL(B, 1);
    DOSOBEL(A, 0);
    LOADCOL(A, 2);
    DOSOBEL(B, 1);
    LOADCOL(B, 3);
    DOSOBEL(A, 2);
    DOSOBEL(B, 3);

    // ---- W fragments + epilogue constants: issue before barrier ----
    bf16x8 wf[18];
#pragma unroll
    for (int i = 0; i < 18; ++i)
        wf[i] = ((const bf16x8*)wt)[i * 64 + lane];

    float b1v[4], w2v[4];
#pragma unroll
    for (int r = 0; r < 4; ++r) {
        int m = 4 * (lane >> 4) + r;
        b1v[r] = b1[m];
        w2v[r] = w2[m];
    }
    const float b2v = b2[0];

    __syncthreads();

    // ---- conv1 via MFMA: wave w handles pixel tiles {w, w+4, w+8, ...} ----
    const int n   = lane & 15;          // pixel within tile (MFMA N)
    const int g16 = (lane >> 4) * 16;   // 8-channel chunk byte offset
    const int DOFF[9] = {0, 1, 2, PS, PS + 1, PS + 2, 2 * PS, 2 * PS + 1, 2 * PS + 2};

#pragma unroll 1
    for (int nt = wave; nt < 19; nt += 4) {
        int p  = nt * 16 + n;
        int pv = p > 288 ? 288 : p;     // clamp dead lanes of last tile
        int pi = pv / 17, pj = pv - pi * 17;
        int base = (pi * PS + pj) * 128 + g16;

        f32x4 acc = {0.f, 0.f, 0.f, 0.f};
#pragma unroll
        for (int d = 0; d < 9; ++d) {
            int off = base + DOFF[d] * 128;
            bf16x8 bfA = *(const bf16x8*)(frq + swz(off));
            bf16x8 bfB = *(const bf16x8*)(frq + swz(off + 64));
            acc = __builtin_amdgcn_mfma_f32_16x16x32_bf16(wf[2 * d],     bfA, acc, 0, 0, 0);
            acc = __builtin_amdgcn_mfma_f32_16x16x32_bf16(wf[2 * d + 1], bfB, acc, 0, 0, 0);
        }

        float part = 0.f;
#pragma unroll
        for (int r = 0; r < 4; ++r)
            part = fmaf(w2v[r], fmaxf(acc[r] + b1v[r], 0.f), part);
        part += __shfl_xor(part, 16);
        part += __shfl_xor(part, 32);

        if (lane < 16 && p < 289) {
            float pre = part + b2v;
            float s = 1.f / (1.f + expf(-pre));
            s = fminf(fmaxf(s, 0.05f), 0.95f);
            out[((size_t)(b * 510 + h0 + pi)) * 510 + (w0 + pj)] = s;
        }
    }
}

extern "C" void kernel_launch(void* const* d_in, const int* in_sizes, int n_in,
                              void* d_out, int out_size, void* d_ws, size_t ws_size,
                              hipStream_t stream) {
    const float* x       = (const float*)d_in[0];
    const float* sobel_w = (const float*)d_in[1];
    const float* w1      = (const float*)d_in[2];
    const float* b1      = (const float*)d_in[3];
    const float* w2      = (const float*)d_in[4];
    const float* b2      = (const float*)d_in[5];
    float* out = (float*)d_out;
    unsigned short* wtab = (unsigned short*)d_ws;   // 18*64*16 = 18432 B

    prep_w1<<<dim3(18), dim3(64), 0, stream>>>(w1, wtab);
    fasa_mfma<<<dim3(3600), dim3(NT), 0, stream>>>(x, sobel_w, wtab, b1, w2, b2, out);
}

// Round 6
// 123.791 us; speedup vs baseline: 8.5931x; 1.0384x over previous
//
#include <hip/hip_runtime.h>

// FrequencyAwareSpatialAttention via MFMA, packed-fp32 sobel, DPP shifts.
// Per block (one 17x17 window, 8 waves):
//   staging: lane = (pair_group, column j); loads both channels of a pair as
//   float2 columns (scalar-base + 32-bit voffset), packed sobel (v_pk_fma_f32),
//   horizontal combine via DPP wave_shr:1 / wave_shl:1 (VALU, no DS),
//   pack via v_cvt_pk_bf16_f32, write frq[pp][c] (swizzled).
//   conv 64->16 3x3 (pad 1): 9 offsets x 2 mfma_f32_16x16x32_bf16, K=64
//   + b1, relu, 1x1 conv 16->1 + b2, sigmoid, clip, scatter.

#define WSZ 17
#define PS  19            // padded 17+2
#define PSS (PS * PS)     // 361
#define NT  512           // 8 waves
#define CH  (510 * 510)   // floats per channel plane

typedef __attribute__((ext_vector_type(8))) short bf16x8;
typedef __attribute__((ext_vector_type(4))) float f32x4;
typedef __attribute__((ext_vector_type(2))) float f32x2;

// XOR swizzle: involution within each 128B frq row (row = padded pixel).
__device__ __forceinline__ int swz(int off) {
    return off ^ (((off >> 7) & 7) << 4);
}

__device__ __forceinline__ unsigned short f2bf(float f) {
    union { float f; unsigned u; } v; v.f = f;
    unsigned u = v.u;
    unsigned r = u + 0x7fffu + ((u >> 16) & 1u);   // RNE
    return (unsigned short)(r >> 16);
}

// lane i <- lane i-1 (wave_shr:1), lane 0 <- 0
__device__ __forceinline__ float dpp_shr1(float v) {
    return __int_as_float(
        __builtin_amdgcn_update_dpp(0, __float_as_int(v), 0x138, 0xf, 0xf, true));
}
// lane i <- lane i+1 (wave_shl:1), lane 63 <- 0
__device__ __forceinline__ float dpp_shl1(float v) {
    return __int_as_float(
        __builtin_amdgcn_update_dpp(0, __float_as_int(v), 0x130, 0xf, 0xf, true));
}

// Pre-kernel: transpose+convert w1 [16][64][3][3] fp32 into A-fragment order.
// Fragment (dij, ks): lane l holds A[m = l&15][k = ks*32 + 8*(l>>4) + j], j=0..7.
__global__ void prep_w1(const float* __restrict__ w1, unsigned short* __restrict__ wt) {
    const int dij = blockIdx.x >> 1;
    const int ks  = blockIdx.x & 1;
    const int l   = threadIdx.x;           // 0..63
    const int m   = l & 15;
    const int kb  = ks * 32 + 8 * (l >> 4);
    bf16x8 v;
#pragma unroll
    for (int jj = 0; jj < 8; ++jj)
        v[jj] = (short)f2bf(w1[m * 576 + (kb + jj) * 9 + dij]);
    ((bf16x8*)wt)[blockIdx.x * 64 + l] = v;
}

__global__ __launch_bounds__(NT, 4)
void fasa_mfma(const float* __restrict__ x,
               const float* __restrict__ sobel_w,
               const unsigned short* __restrict__ wt,
               const float* __restrict__ b1,
               const float* __restrict__ w2,
               const float* __restrict__ b2,
               float* __restrict__ out)
{
    __shared__ __align__(16) char frq[PSS * 128];   // 46.2 KB, [pp][c] bf16 swizzled

    const int t    = threadIdx.x;
    const int lane = t & 63;
    const int wave = __builtin_amdgcn_readfirstlane(t >> 6);

    const int win = blockIdx.x;                     // b*900 + wh*30 + ww
    const int b   = win / 900;
    const int rem = win % 900;
    const int h0  = (rem / 30) * WSZ;
    const int w0  = (rem % 30) * WSZ;

    // ---- zero the 72 border rows of frq (interior rows all get written) ----
    for (int u = t; u < 72 * 8; u += NT) {
        int r = u >> 3, k = u & 7;
        int row;
        if      (r < 19) row = r;                   // pi == 0
        else if (r < 38) row = 342 + (r - 19);      // pi == 18
        else if (r < 55) row = (r - 37) * PS;       // pj == 0, pi 1..17
        else             row = (r - 54) * PS + 18;  // pj == 18, pi 1..17
        *(f32x4*)(frq + row * 128 + k * 16) = (f32x4){0.f, 0.f, 0.f, 0.f};
    }

    // ---- staging: lane = (grp, j); pair slot = 2*wave + grp; q = 0,1 ----
    const int j   = lane & 31;       // column, active when j < 17
    const int grp = lane >> 5;       // which pair of this wave's two
    const bool jac = (j < 17);

    // wave-uniform base (channel 4*wave); per-lane 32-bit byte offsets
    const float* xbase = x + ((size_t)(b * 64 + 4 * wave)) * CH
                           + (size_t)h0 * 510 + w0;
    const unsigned voffx = (unsigned)((grp * 2 * CH + j) * 4);
    const unsigned voffy = voffx + (unsigned)(CH * 4);

    auto LOADCOL = [&](f32x2* xr, int q) {
        const char* bp = (const char*)(xbase + (size_t)q * 32 * CH);
        xr[0] = (f32x2){0.f, 0.f}; xr[18] = (f32x2){0.f, 0.f};
        if (jac) {
#pragma unroll
            for (int i = 0; i < 17; ++i) {
                xr[i + 1].x = *(const float*)(bp + (voffx + (unsigned)i * 2040u));
                xr[i + 1].y = *(const float*)(bp + (voffy + (unsigned)i * 2040u));
            }
        } else {
#pragma unroll
            for (int i = 0; i < 17; ++i) xr[i + 1] = (f32x2){0.f, 0.f};
        }
    };

    auto DOSOBEL = [&](const f32x2* xr, int q) {
        const int c0 = 4 * wave + 2 * grp + 32 * q;   // first channel of pair
        f32x2 sw[9];
#pragma unroll
        for (int k = 0; k < 9; ++k) {
            sw[k].x = sobel_w[c0 * 9 + k];
            sw[k].y = sobel_w[(c0 + 1) * 9 + k];
        }
        const int pairOff = (c0 >> 1) * 4;            // pair byte offset in frq row
#pragma unroll
        for (int i = 0; i < 17; ++i) {
            f32x2 p0 = __builtin_elementwise_fma(sw[0], xr[i],
                         __builtin_elementwise_fma(sw[3], xr[i + 1], sw[6] * xr[i + 2]));
            f32x2 p1 = __builtin_elementwise_fma(sw[1], xr[i],
                         __builtin_elementwise_fma(sw[4], xr[i + 1], sw[7] * xr[i + 2]));
            f32x2 p2 = __builtin_elementwise_fma(sw[2], xr[i],
                         __builtin_elementwise_fma(sw[5], xr[i + 1], sw[8] * xr[i + 2]));
            // o(j) = p0(j-1) + p1(j) + p2(j+1); zero cols at j>=17 supply pads
            f32x2 o;
            o.x = p1.x + dpp_shr1(p0.x) + dpp_shl1(p2.x);
            o.y = p1.y + dpp_shr1(p0.y) + dpp_shl1(p2.y);
            unsigned pkv;
            asm("v_cvt_pk_bf16_f32 %0, %1, %2" : "=v"(pkv) : "v"(o.x), "v"(o.y));
            if (jac)
                *(unsigned*)(frq + swz(((i + 1) * PS + (j + 1)) * 128 + pairOff)) = pkv;
        }
    };

    // A/B double-buffered: loads overlap sobel
    f32x2 A[19], B[19];
    LOADCOL(A, 0);
    LOADCOL(B, 1);
    DOSOBEL(A, 0);
    DOSOBEL(B, 1);

    // ---- W fragments + epilogue constants: issue before barrier ----
    bf16x8 wf[18];
#pragma unroll
    for (int i = 0; i < 18; ++i)
        wf[i] = ((const bf16x8*)wt)[i * 64 + lane];

    float b1v[4], w2v[4];
#pragma unroll
    for (int r = 0; r < 4; ++r) {
        int m = 4 * (lane >> 4) + r;
        b1v[r] = b1[m];
        w2v[r] = w2[m];
    }
    const float b2v = b2[0];

    __syncthreads();

    // ---- conv1 via MFMA: wave w handles pixel tiles {w, w+8, w+16} ----
    const int n   = lane & 15;          // pixel within tile (MFMA N)
    const int g16 = (lane >> 4) * 16;   // 8-channel chunk byte offset
    const int DOFF[9] = {0, 1, 2, PS, PS + 1, PS + 2, 2 * PS, 2 * PS + 1, 2 * PS + 2};

#pragma unroll 1
    for (int nt = wave; nt < 19; nt += 8) {
        int p  = nt * 16 + n;
        int pv = p > 288 ? 288 : p;     // clamp dead lanes of last tile
        int pi = pv / 17, pj = pv - pi * 17;
        int base = (pi * PS + pj) * 128 + g16;

        f32x4 acc = {0.f, 0.f, 0.f, 0.f};
#pragma unroll
        for (int d = 0; d < 9; ++d) {
            int off = base + DOFF[d] * 128;
            bf16x8 bfA = *(const bf16x8*)(frq + swz(off));
            bf16x8 bfB = *(const bf16x8*)(frq + swz(off + 64));
            acc = __builtin_amdgcn_mfma_f32_16x16x32_bf16(wf[2 * d],     bfA, acc, 0, 0, 0);
            acc = __builtin_amdgcn_mfma_f32_16x16x32_bf16(wf[2 * d + 1], bfB, acc, 0, 0, 0);
        }

        float part = 0.f;
#pragma unroll
        for (int r = 0; r < 4; ++r)
            part = fmaf(w2v[r], fmaxf(acc[r] + b1v[r], 0.f), part);
        part += __shfl_xor(part, 16);
        part += __shfl_xor(part, 32);

        if (lane < 16 && p < 289) {
            float pre = part + b2v;
            float s = 1.f / (1.f + expf(-pre));
            s = fminf(fmaxf(s, 0.05f), 0.95f);
            out[((size_t)(b * 510 + h0 + pi)) * 510 + (w0 + pj)] = s;
        }
    }
}

extern "C" void kernel_launch(void* const* d_in, const int* in_sizes, int n_in,
                              void* d_out, int out_size, void* d_ws, size_t ws_size,
                              hipStream_t stream) {
    const float* x       = (const float*)d_in[0];
    const float* sobel_w = (const float*)d_in[1];
    const float* w1      = (const float*)d_in[2];
    const float* b1      = (const float*)d_in[3];
    const float* w2      = (const float*)d_in[4];
    const float* b2      = (const float*)d_in[5];
    float* out = (float*)d_out;
    unsigned short* wtab = (unsigned short*)d_ws;   // 18*64*16 = 18432 B

    prep_w1<<<dim3(18), dim3(64), 0, stream>>>(w1, wtab);
    fasa_mfma<<<dim3(3600), dim3(NT), 0, stream>>>(x, sobel_w, wtab, b1, w2, b2, out);
}

// Round 7
// 93.634 us; speedup vs baseline: 11.3606x; 1.3221x over previous
//
#include <hip/hip_runtime.h>

// FrequencyAwareSpatialAttention via MFMA, packed-fp32 sobel, DPP shifts,
// wave-uniform sobel weights (all channels share one 3x3 — tiled in setup),
// XCD-chunked block swizzle for L2 locality of window-boundary lines.
// Per block (one 17x17 window, 8 waves):
//   staging: lane = (pair_group, column j); loads both channels of a pair as
//   float2 columns (scalar-base + 32-bit voffset), packed sobel (v_pk_fma_f32),
//   horizontal combine via DPP wave_shr:1 / wave_shl:1 (VALU, no DS),
//   pack via v_cvt_pk_bf16_f32, write frq[pp][c] (swizzled).
//   conv 64->16 3x3 (pad 1): 9 offsets x 2 mfma_f32_16x16x32_bf16, K=64
//   + b1, relu, 1x1 conv 16->1 + b2, sigmoid, clip, scatter.

#define WSZ 17
#define PS  19            // padded 17+2
#define PSS (PS * PS)     // 361
#define NT  512           // 8 waves
#define CH  (510 * 510)   // floats per channel plane

typedef __attribute__((ext_vector_type(8))) short bf16x8;
typedef __attribute__((ext_vector_type(4))) float f32x4;
typedef __attribute__((ext_vector_type(2))) float f32x2;

// XOR swizzle: involution within each 128B frq row (row = padded pixel).
__device__ __forceinline__ int swz(int off) {
    return off ^ (((off >> 7) & 7) << 4);
}

__device__ __forceinline__ unsigned short f2bf(float f) {
    union { float f; unsigned u; } v; v.f = f;
    unsigned u = v.u;
    unsigned r = u + 0x7fffu + ((u >> 16) & 1u);   // RNE
    return (unsigned short)(r >> 16);
}

// lane i <- lane i-1 (wave_shr:1), lane 0 <- 0
__device__ __forceinline__ float dpp_shr1(float v) {
    return __int_as_float(
        __builtin_amdgcn_update_dpp(0, __float_as_int(v), 0x138, 0xf, 0xf, true));
}
// lane i <- lane i+1 (wave_shl:1), lane 63 <- 0
__device__ __forceinline__ float dpp_shl1(float v) {
    return __int_as_float(
        __builtin_amdgcn_update_dpp(0, __float_as_int(v), 0x130, 0xf, 0xf, true));
}

// Pre-kernel: transpose+convert w1 [16][64][3][3] fp32 into A-fragment order.
// Fragment (dij, ks): lane l holds A[m = l&15][k = ks*32 + 8*(l>>4) + j], j=0..7.
__global__ void prep_w1(const float* __restrict__ w1, unsigned short* __restrict__ wt) {
    const int dij = blockIdx.x >> 1;
    const int ks  = blockIdx.x & 1;
    const int l   = threadIdx.x;           // 0..63
    const int m   = l & 15;
    const int kb  = ks * 32 + 8 * (l >> 4);
    bf16x8 v;
#pragma unroll
    for (int jj = 0; jj < 8; ++jj)
        v[jj] = (short)f2bf(w1[m * 576 + (kb + jj) * 9 + dij]);
    ((bf16x8*)wt)[blockIdx.x * 64 + l] = v;
}

__global__ __launch_bounds__(NT, 4)
void fasa_mfma(const float* __restrict__ x,
               const float* __restrict__ sobel_w,
               const unsigned short* __restrict__ wt,
               const float* __restrict__ b1,
               const float* __restrict__ w2,
               const float* __restrict__ b2,
               float* __restrict__ out)
{
    __shared__ __align__(16) char frq[PSS * 128];   // 46.2 KB, [pp][c] bf16 swizzled

    const int t    = threadIdx.x;
    const int lane = t & 63;
    const int wave = __builtin_amdgcn_readfirstlane(t >> 6);

    // XCD-chunked swizzle: HW maps bid%8 -> XCD; give each XCD a contiguous
    // run of 450 windows (15 window-rows) so boundary cache lines shared by
    // horizontally-adjacent windows hit the same L2. 3600 = 8*450 (bijective).
    const int bid = blockIdx.x;
    const int win = (bid & 7) * 450 + (bid >> 3);   // b*900 + wh*30 + ww
    const int b   = win / 900;
    const int rem = win % 900;
    const int h0  = (rem / 30) * WSZ;
    const int w0  = (rem % 30) * WSZ;

    // ---- zero the 72 border rows of frq (interior rows all get written) ----
    for (int u = t; u < 72 * 8; u += NT) {
        int r = u >> 3, k = u & 7;
        int row;
        if      (r < 19) row = r;                   // pi == 0
        else if (r < 38) row = 342 + (r - 19);      // pi == 18
        else if (r < 55) row = (r - 37) * PS;       // pj == 0, pi 1..17
        else             row = (r - 54) * PS + 18;  // pj == 18, pi 1..17
        *(f32x4*)(frq + row * 128 + k * 16) = (f32x4){0.f, 0.f, 0.f, 0.f};
    }

    // ---- sobel weights: ALL channels share one 3x3 (tiled in setup) ----
    // uniform address -> scalar loads, one copy in registers for all tasks
    float sw[9];
#pragma unroll
    for (int k = 0; k < 9; ++k) sw[k] = sobel_w[k];

    // ---- staging: lane = (grp, j); pair slot = 2*wave + grp; q = 0,1 ----
    const int j   = lane & 31;       // column, active when j < 17
    const int grp = lane >> 5;       // which pair of this wave's two
    const bool jac = (j < 17);

    // wave-uniform base (channel 4*wave); per-lane 32-bit byte offsets
    const float* xbase = x + ((size_t)(b * 64 + 4 * wave)) * CH
                           + (size_t)h0 * 510 + w0;
    const unsigned voffx = (unsigned)((grp * 2 * CH + j) * 4);
    const unsigned voffy = voffx + (unsigned)(CH * 4);

    auto LOADCOL = [&](f32x2* xr, int q) {
        const char* bp = (const char*)(xbase + (size_t)q * 32 * CH);
        xr[0] = (f32x2){0.f, 0.f}; xr[18] = (f32x2){0.f, 0.f};
        if (jac) {
#pragma unroll
            for (int i = 0; i < 17; ++i) {
                xr[i + 1].x = *(const float*)(bp + (voffx + (unsigned)i * 2040u));
                xr[i + 1].y = *(const float*)(bp + (voffy + (unsigned)i * 2040u));
            }
        } else {
#pragma unroll
            for (int i = 0; i < 17; ++i) xr[i + 1] = (f32x2){0.f, 0.f};
        }
    };

    auto DOSOBEL = [&](const f32x2* xr, int q) {
        const int pr = 2 * wave + grp + 16 * q;       // pair index 0..31
        const int pairOff = pr * 4;                   // pair byte offset in frq row
#pragma unroll
        for (int i = 0; i < 17; ++i) {
            f32x2 p0 = sw[0] * xr[i] + sw[3] * xr[i + 1] + sw[6] * xr[i + 2];
            f32x2 p1 = sw[1] * xr[i] + sw[4] * xr[i + 1] + sw[7] * xr[i + 2];
            f32x2 p2 = sw[2] * xr[i] + sw[5] * xr[i + 1] + sw[8] * xr[i + 2];
            // o(j) = p0(j-1) + p1(j) + p2(j+1); zero cols at j>=17 supply pads
            f32x2 o;
            o.x = p1.x + dpp_shr1(p0.x) + dpp_shl1(p2.x);
            o.y = p1.y + dpp_shr1(p0.y) + dpp_shl1(p2.y);
            unsigned pkv;
            asm("v_cvt_pk_bf16_f32 %0, %1, %2" : "=v"(pkv) : "v"(o.x), "v"(o.y));
            if (jac)
                *(unsigned*)(frq + swz(((i + 1) * PS + (j + 1)) * 128 + pairOff)) = pkv;
        }
    };

    // A/B double-buffered: loads overlap sobel
    f32x2 A[19], B[19];
    LOADCOL(A, 0);
    LOADCOL(B, 1);
    DOSOBEL(A, 0);
    DOSOBEL(B, 1);

    // ---- W fragments + epilogue constants: issue before barrier ----
    bf16x8 wf[18];
#pragma unroll
    for (int i = 0; i < 18; ++i)
        wf[i] = ((const bf16x8*)wt)[i * 64 + lane];

    float b1v[4], w2v[4];
#pragma unroll
    for (int r = 0; r < 4; ++r) {
        int m = 4 * (lane >> 4) + r;
        b1v[r] = b1[m];
        w2v[r] = w2[m];
    }
    const float b2v = b2[0];

    __syncthreads();

    // ---- conv1 via MFMA: wave w handles pixel tiles {w, w+8, w+16} ----
    const int n   = lane & 15;          // pixel within tile (MFMA N)
    const int g16 = (lane >> 4) * 16;   // 8-channel chunk byte offset
    const int DOFF[9] = {0, 1, 2, PS, PS + 1, PS + 2, 2 * PS, 2 * PS + 1, 2 * PS + 2};

#pragma unroll 1
    for (int nt = wave; nt < 19; nt += 8) {
        int p  = nt * 16 + n;
        int pv = p > 288 ? 288 : p;     // clamp dead lanes of last tile
        int pi = pv / 17, pj = pv - pi * 17;
        int base = (pi * PS + pj) * 128 + g16;

        f32x4 acc = {0.f, 0.f, 0.f, 0.f};
#pragma unroll
        for (int d = 0; d < 9; ++d) {
            int off = base + DOFF[d] * 128;
            bf16x8 bfA = *(const bf16x8*)(frq + swz(off));
            bf16x8 bfB = *(const bf16x8*)(frq + swz(off + 64));
            acc = __builtin_amdgcn_mfma_f32_16x16x32_bf16(wf[2 * d],     bfA, acc, 0, 0, 0);
            acc = __builtin_amdgcn_mfma_f32_16x16x32_bf16(wf[2 * d + 1], bfB, acc, 0, 0, 0);
        }

        float part = 0.f;
#pragma unroll
        for (int r = 0; r < 4; ++r)
            part = fmaf(w2v[r], fmaxf(acc[r] + b1v[r], 0.f), part);
        part += __shfl_xor(part, 16);
        part += __shfl_xor(part, 32);

        if (lane < 16 && p < 289) {
            float pre = part + b2v;
            float s = 1.f / (1.f + expf(-pre));
            s = fminf(fmaxf(s, 0.05f), 0.95f);
            out[((size_t)(b * 510 + h0 + pi)) * 510 + (w0 + pj)] = s;
        }
    }
}

extern "C" void kernel_launch(void* const* d_in, const int* in_sizes, int n_in,
                              void* d_out, int out_size, void* d_ws, size_t ws_size,
                              hipStream_t stream) {
    const float* x       = (const float*)d_in[0];
    const float* sobel_w = (const float*)d_in[1];
    const float* w1      = (const float*)d_in[2];
    const float* b1      = (const float*)d_in[3];
    const float* w2      = (const float*)d_in[4];
    const float* b2      = (const float*)d_in[5];
    float* out = (float*)d_out;
    unsigned short* wtab = (unsigned short*)d_ws;   // 18*64*16 = 18432 B

    prep_w1<<<dim3(18), dim3(64), 0, stream>>>(w1, wtab);
    fasa_mfma<<<dim3(3600), dim3(NT), 0, stream>>>(x, sobel_w, wtab, b1, w2, b2, out);
}

// Round 8
// 93.049 us; speedup vs baseline: 11.4321x; 1.0063x over previous
//
#include <hip/hip_runtime.h>

// FrequencyAwareSpatialAttention via MFMA, packed-fp32 sobel, DPP shifts,
// wave-uniform sobel weights, XCD-chunked block swizzle, and a pinned
// 68-deep load cluster (sched_barrier) so HBM/L3 latency is covered by
// in-flight loads instead of exposed per 8-load batch.
// Per block (one 17x17 window, 8 waves):
//   staging: lane = (pair_group, column j); loads both channels of a pair as
//   float2 columns (scalar-base + 32-bit voffset), packed sobel (v_pk_fma_f32),
//   horizontal combine via DPP wave_shr:1 / wave_shl:1 (VALU, no DS),
//   pack via v_cvt_pk_bf16_f32, write frq[pp][c] (swizzled).
//   conv 64->16 3x3 (pad 1): 9 offsets x 2 mfma_f32_16x16x32_bf16, K=64
//   + b1, relu, 1x1 conv 16->1 + b2, sigmoid, clip, scatter.

#define WSZ 17
#define PS  19            // padded 17+2
#define PSS (PS * PS)     // 361
#define NT  512           // 8 waves
#define CH  (510 * 510)   // floats per channel plane

typedef __attribute__((ext_vector_type(8))) short bf16x8;
typedef __attribute__((ext_vector_type(4))) float f32x4;
typedef __attribute__((ext_vector_type(2))) float f32x2;

// XOR swizzle: involution within each 128B frq row (row = padded pixel).
__device__ __forceinline__ int swz(int off) {
    return off ^ (((off >> 7) & 7) << 4);
}

__device__ __forceinline__ unsigned short f2bf(float f) {
    union { float f; unsigned u; } v; v.f = f;
    unsigned u = v.u;
    unsigned r = u + 0x7fffu + ((u >> 16) & 1u);   // RNE
    return (unsigned short)(r >> 16);
}

// lane i <- lane i-1 (wave_shr:1), lane 0 <- 0
__device__ __forceinline__ float dpp_shr1(float v) {
    return __int_as_float(
        __builtin_amdgcn_update_dpp(0, __float_as_int(v), 0x138, 0xf, 0xf, true));
}
// lane i <- lane i+1 (wave_shl:1), lane 63 <- 0
__device__ __forceinline__ float dpp_shl1(float v) {
    return __int_as_float(
        __builtin_amdgcn_update_dpp(0, __float_as_int(v), 0x130, 0xf, 0xf, true));
}

// Pre-kernel: transpose+convert w1 [16][64][3][3] fp32 into A-fragment order.
// Fragment (dij, ks): lane l holds A[m = l&15][k = ks*32 + 8*(l>>4) + j], j=0..7.
__global__ void prep_w1(const float* __restrict__ w1, unsigned short* __restrict__ wt) {
    const int dij = blockIdx.x >> 1;
    const int ks  = blockIdx.x & 1;
    const int l   = threadIdx.x;           // 0..63
    const int m   = l & 15;
    const int kb  = ks * 32 + 8 * (l >> 4);
    bf16x8 v;
#pragma unroll
    for (int jj = 0; jj < 8; ++jj)
        v[jj] = (short)f2bf(w1[m * 576 + (kb + jj) * 9 + dij]);
    ((bf16x8*)wt)[blockIdx.x * 64 + l] = v;
}

__global__ __launch_bounds__(NT, 4)
void fasa_mfma(const float* __restrict__ x,
               const float* __restrict__ sobel_w,
               const unsigned short* __restrict__ wt,
               const float* __restrict__ b1,
               const float* __restrict__ w2,
               const float* __restrict__ b2,
               float* __restrict__ out)
{
    __shared__ __align__(16) char frq[PSS * 128];   // 46.2 KB, [pp][c] bf16 swizzled

    const int t    = threadIdx.x;
    const int lane = t & 63;
    const int wave = __builtin_amdgcn_readfirstlane(t >> 6);

    // XCD-chunked swizzle: HW maps bid%8 -> XCD; give each XCD a contiguous
    // run of 450 windows (15 window-rows). 3600 = 8*450 (bijective).
    const int bid = blockIdx.x;
    const int win = (bid & 7) * 450 + (bid >> 3);   // b*900 + wh*30 + ww
    const int b   = win / 900;
    const int rem = win % 900;
    const int h0  = (rem / 30) * WSZ;
    const int w0  = (rem % 30) * WSZ;

    // ---- zero the 72 border rows of frq (interior rows all get written) ----
    for (int u = t; u < 72 * 8; u += NT) {
        int r = u >> 3, k = u & 7;
        int row;
        if      (r < 19) row = r;                   // pi == 0
        else if (r < 38) row = 342 + (r - 19);      // pi == 18
        else if (r < 55) row = (r - 37) * PS;       // pj == 0, pi 1..17
        else             row = (r - 54) * PS + 18;  // pj == 18, pi 1..17
        *(f32x4*)(frq + row * 128 + k * 16) = (f32x4){0.f, 0.f, 0.f, 0.f};
    }

    // ---- sobel weights: ALL channels share one 3x3 (tiled in setup) ----
    float sw[9];
#pragma unroll
    for (int k = 0; k < 9; ++k) sw[k] = sobel_w[k];

    // ---- staging: lane = (grp, j); pair slot = 2*wave + grp; q = 0,1 ----
    const int j   = lane & 31;       // column, active when j < 17
    const int grp = lane >> 5;       // which pair of this wave's two
    const bool jac = (j < 17);

    // wave-uniform base (channel 4*wave); per-lane 32-bit byte offsets
    const float* xbase = x + ((size_t)(b * 64 + 4 * wave)) * CH
                           + (size_t)h0 * 510 + w0;
    const unsigned voffx = (unsigned)((grp * 2 * CH + j) * 4);
    const unsigned voffy = voffx + (unsigned)(CH * 4);

    auto LOADCOL = [&](f32x2* xr, int q) {
        const char* bp = (const char*)(xbase + (size_t)q * 32 * CH);
        xr[0] = (f32x2){0.f, 0.f}; xr[18] = (f32x2){0.f, 0.f};
        if (jac) {
#pragma unroll
            for (int i = 0; i < 17; ++i) {
                xr[i + 1].x = *(const float*)(bp + (voffx + (unsigned)i * 2040u));
                xr[i + 1].y = *(const float*)(bp + (voffy + (unsigned)i * 2040u));
            }
        } else {
#pragma unroll
            for (int i = 0; i < 17; ++i) xr[i + 1] = (f32x2){0.f, 0.f};
        }
    };

    auto DOSOBEL = [&](const f32x2* xr, int q) {
        const int pr = 2 * wave + grp + 16 * q;       // pair index 0..31
        const int pairOff = pr * 4;                   // pair byte offset in frq row
#pragma unroll
        for (int i = 0; i < 17; ++i) {
            f32x2 p0 = sw[0] * xr[i] + sw[3] * xr[i + 1] + sw[6] * xr[i + 2];
            f32x2 p1 = sw[1] * xr[i] + sw[4] * xr[i + 1] + sw[7] * xr[i + 2];
            f32x2 p2 = sw[2] * xr[i] + sw[5] * xr[i + 1] + sw[8] * xr[i + 2];
            // o(j) = p0(j-1) + p1(j) + p2(j+1); zero cols at j>=17 supply pads
            f32x2 o;
            o.x = p1.x + dpp_shr1(p0.x) + dpp_shl1(p2.x);
            o.y = p1.y + dpp_shr1(p0.y) + dpp_shl1(p2.y);
            unsigned pkv;
            asm("v_cvt_pk_bf16_f32 %0, %1, %2" : "=v"(pkv) : "v"(o.x), "v"(o.y));
            if (jac)
                *(unsigned*)(frq + swz(((i + 1) * PS + (j + 1)) * 128 + pairOff)) = pkv;
        }
    };

    // A/B double-buffered: pin ALL 68 loads in flight before any sobel use.
    // Without the sched_barrier the register allocator sinks B's loads below
    // DOSOBEL(A) (VGPR 52 observed) and exposes full memory latency per batch.
    f32x2 A[19], B[19];
    LOADCOL(A, 0);
    LOADCOL(B, 1);
    __builtin_amdgcn_sched_barrier(0);
    DOSOBEL(A, 0);
    DOSOBEL(B, 1);

    // ---- W fragments + epilogue constants: issue before barrier ----
    bf16x8 wf[18];
#pragma unroll
    for (int i = 0; i < 18; ++i)
        wf[i] = ((const bf16x8*)wt)[i * 64 + lane];

    float b1v[4], w2v[4];
#pragma unroll
    for (int r = 0; r < 4; ++r) {
        int m = 4 * (lane >> 4) + r;
        b1v[r] = b1[m];
        w2v[r] = w2[m];
    }
    const float b2v = b2[0];

    __syncthreads();

    // ---- conv1 via MFMA: wave w handles pixel tiles {w, w+8, w+16} ----
    const int n   = lane & 15;          // pixel within tile (MFMA N)
    const int g16 = (lane >> 4) * 16;   // 8-channel chunk byte offset
    const int DOFF[9] = {0, 1, 2, PS, PS + 1, PS + 2, 2 * PS, 2 * PS + 1, 2 * PS + 2};

#pragma unroll 1
    for (int nt = wave; nt < 19; nt += 8) {
        int p  = nt * 16 + n;
        int pv = p > 288 ? 288 : p;     // clamp dead lanes of last tile
        int pi = pv / 17, pj = pv - pi * 17;
        int base = (pi * PS + pj) * 128 + g16;

        f32x4 acc = {0.f, 0.f, 0.f, 0.f};
#pragma unroll
        for (int d = 0; d < 9; ++d) {
            int off = base + DOFF[d] * 128;
            bf16x8 bfA = *(const bf16x8*)(frq + swz(off));
            bf16x8 bfB = *(const bf16x8*)(frq + swz(off + 64));
            acc = __builtin_amdgcn_mfma_f32_16x16x32_bf16(wf[2 * d],     bfA, acc, 0, 0, 0);
            acc = __builtin_amdgcn_mfma_f32_16x16x32_bf16(wf[2 * d + 1], bfB, acc, 0, 0, 0);
        }

        float part = 0.f;
#pragma unroll
        for (int r = 0; r < 4; ++r)
            part = fmaf(w2v[r], fmaxf(acc[r] + b1v[r], 0.f), part);
        part += __shfl_xor(part, 16);
        part += __shfl_xor(part, 32);

        if (lane < 16 && p < 289) {
            float pre = part + b2v;
            float s = 1.f / (1.f + expf(-pre));
            s = fminf(fmaxf(s, 0.05f), 0.95f);
            out[((size_t)(b * 510 + h0 + pi)) * 510 + (w0 + pj)] = s;
        }
    }
}

extern "C" void kernel_launch(void* const* d_in, const int* in_sizes, int n_in,
                              void* d_out, int out_size, void* d_ws, size_t ws_size,
                              hipStream_t stream) {
    const float* x       = (const float*)d_in[0];
    const float* sobel_w = (const float*)d_in[1];
    const float* w1      = (const float*)d_in[2];
    const float* b1      = (const float*)d_in[3];
    const float* w2      = (const float*)d_in[4];
    const float* b2      = (const float*)d_in[5];
    float* out = (float*)d_out;
    unsigned short* wtab = (unsigned short*)d_ws;   // 18*64*16 = 18432 B

    prep_w1<<<dim3(18), dim3(64), 0, stream>>>(w1, wtab);
    fasa_mfma<<<dim3(3600), dim3(NT), 0, stream>>>(x, sobel_w, wtab, b1, w2, b2, out);
}

// Round 9
// 91.949 us; speedup vs baseline: 11.5689x; 1.0120x over previous
//
#include <hip/hip_runtime.h>

// FrequencyAwareSpatialAttention via MFMA, packed-fp32 sobel, DPP shifts,
// wave-uniform sobel weights, XCD-chunked block swizzle.
// KEY CHANGE (R9): LDS padded past 160/3 KB so the compiler's LDS-limited
// occupancy target drops 3->2 blocks/CU, raising its VGPR budget 85->128.
// This lets the full 68-load A/B staging cluster stay live in registers
// (R8 showed VGPR=52: the scheduler batched loads to hit the 3-block VGPR
// target, exposing memory latency per batch; sched_barrier alone was a no-op).
// Per block (one 17x17 window, 8 waves):
//   staging: lane = (pair_group, column j); loads both channels of a pair as
//   float2 columns (scalar-base + 32-bit voffset), packed sobel (v_pk_fma_f32),
//   horizontal combine via DPP wave_shr:1 / wave_shl:1 (VALU, no DS),
//   pack via v_cvt_pk_bf16_f32, write frq[pp][c] (swizzled).
//   conv 64->16 3x3 (pad 1): 9 offsets x 2 mfma_f32_16x16x32_bf16, K=64
//   + b1, relu, 1x1 conv 16->1 + b2, sigmoid, clip, scatter.

#define WSZ 17
#define PS  19            // padded 17+2
#define PSS (PS * PS)     // 361
#define NT  512           // 8 waves
#define CH  (510 * 510)   // floats per channel plane
// Occupancy-target pad: 46208 -> 56576 B (> 160KiB/3 = 54613) forces the
// compiler to plan for 2 blocks/CU (4 waves/SIMD) => VGPR budget 128.
#define FRQ_PAD 10368

typedef __attribute__((ext_vector_type(8))) short bf16x8;
typedef __attribute__((ext_vector_type(4))) float f32x4;
typedef __attribute__((ext_vector_type(2))) float f32x2;

// XOR swizzle: involution within each 128B frq row (row = padded pixel).
__device__ __forceinline__ int swz(int off) {
    return off ^ (((off >> 7) & 7) << 4);
}

__device__ __forceinline__ unsigned short f2bf(float f) {
    union { float f; unsigned u; } v; v.f = f;
    unsigned u = v.u;
    unsigned r = u + 0x7fffu + ((u >> 16) & 1u);   // RNE
    return (unsigned short)(r >> 16);
}

// lane i <- lane i-1 (wave_shr:1), lane 0 <- 0
__device__ __forceinline__ float dpp_shr1(float v) {
    return __int_as_float(
        __builtin_amdgcn_update_dpp(0, __float_as_int(v), 0x138, 0xf, 0xf, true));
}
// lane i <- lane i+1 (wave_shl:1), lane 63 <- 0
__device__ __forceinline__ float dpp_shl1(float v) {
    return __int_as_float(
        __builtin_amdgcn_update_dpp(0, __float_as_int(v), 0x130, 0xf, 0xf, true));
}

// Pre-kernel: transpose+convert w1 [16][64][3][3] fp32 into A-fragment order.
// Fragment (dij, ks): lane l holds A[m = l&15][k = ks*32 + 8*(l>>4) + j], j=0..7.
__global__ void prep_w1(const float* __restrict__ w1, unsigned short* __restrict__ wt) {
    const int dij = blockIdx.x >> 1;
    const int ks  = blockIdx.x & 1;
    const int l   = threadIdx.x;           // 0..63
    const int m   = l & 15;
    const int kb  = ks * 32 + 8 * (l >> 4);
    bf16x8 v;
#pragma unroll
    for (int jj = 0; jj < 8; ++jj)
        v[jj] = (short)f2bf(w1[m * 576 + (kb + jj) * 9 + dij]);
    ((bf16x8*)wt)[blockIdx.x * 64 + l] = v;
}

__global__ __launch_bounds__(NT, 4)
void fasa_mfma(const float* __restrict__ x,
               const float* __restrict__ sobel_w,
               const unsigned short* __restrict__ wt,
               const float* __restrict__ b1,
               const float* __restrict__ w2,
               const float* __restrict__ b2,
               float* __restrict__ out)
{
    // 46.2 KB used + pad (pad is never touched; it only raises the
    // compiler/runtime LDS size to lower the occupancy target to 2 blocks/CU)
    __shared__ __align__(16) char frq[PSS * 128 + FRQ_PAD];

    const int t    = threadIdx.x;
    const int lane = t & 63;
    const int wave = __builtin_amdgcn_readfirstlane(t >> 6);

    // XCD-chunked swizzle: HW maps bid%8 -> XCD; give each XCD a contiguous
    // run of 450 windows (15 window-rows). 3600 = 8*450 (bijective).
    const int bid = blockIdx.x;
    const int win = (bid & 7) * 450 + (bid >> 3);   // b*900 + wh*30 + ww
    const int b   = win / 900;
    const int rem = win % 900;
    const int h0  = (rem / 30) * WSZ;
    const int w0  = (rem % 30) * WSZ;

    // ---- zero the 72 border rows of frq (interior rows all get written) ----
    for (int u = t; u < 72 * 8; u += NT) {
        int r = u >> 3, k = u & 7;
        int row;
        if      (r < 19) row = r;                   // pi == 0
        else if (r < 38) row = 342 + (r - 19);      // pi == 18
        else if (r < 55) row = (r - 37) * PS;       // pj == 0, pi 1..17
        else             row = (r - 54) * PS + 18;  // pj == 18, pi 1..17
        *(f32x4*)(frq + row * 128 + k * 16) = (f32x4){0.f, 0.f, 0.f, 0.f};
    }

    // ---- sobel weights: ALL channels share one 3x3 (tiled in setup) ----
    float sw[9];
#pragma unroll
    for (int k = 0; k < 9; ++k) sw[k] = sobel_w[k];

    // ---- staging: lane = (grp, j); pair slot = 2*wave + grp; q = 0,1 ----
    const int j   = lane & 31;       // column, active when j < 17
    const int grp = lane >> 5;       // which pair of this wave's two
    const bool jac = (j < 17);

    // wave-uniform base (channel 4*wave); per-lane 32-bit byte offsets
    const float* xbase = x + ((size_t)(b * 64 + 4 * wave)) * CH
                           + (size_t)h0 * 510 + w0;
    const unsigned voffx = (unsigned)((grp * 2 * CH + j) * 4);
    const unsigned voffy = voffx + (unsigned)(CH * 4);

    auto LOADCOL = [&](f32x2* xr, int q) {
        const char* bp = (const char*)(xbase + (size_t)q * 32 * CH);
        xr[0] = (f32x2){0.f, 0.f}; xr[18] = (f32x2){0.f, 0.f};
        if (jac) {
#pragma unroll
            for (int i = 0; i < 17; ++i) {
                xr[i + 1].x = *(const float*)(bp + (voffx + (unsigned)i * 2040u));
                xr[i + 1].y = *(const float*)(bp + (voffy + (unsigned)i * 2040u));
            }
        } else {
#pragma unroll
            for (int i = 0; i < 17; ++i) xr[i + 1] = (f32x2){0.f, 0.f};
        }
    };

    auto DOSOBEL = [&](const f32x2* xr, int q) {
        const int pr = 2 * wave + grp + 16 * q;       // pair index 0..31
        const int pairOff = pr * 4;                   // pair byte offset in frq row
#pragma unroll
        for (int i = 0; i < 17; ++i) {
            f32x2 p0 = sw[0] * xr[i] + sw[3] * xr[i + 1] + sw[6] * xr[i + 2];
            f32x2 p1 = sw[1] * xr[i] + sw[4] * xr[i + 1] + sw[7] * xr[i + 2];
            f32x2 p2 = sw[2] * xr[i] + sw[5] * xr[i + 1] + sw[8] * xr[i + 2];
            // o(j) = p0(j-1) + p1(j) + p2(j+1); zero cols at j>=17 supply pads
            f32x2 o;
            o.x = p1.x + dpp_shr1(p0.x) + dpp_shl1(p2.x);
            o.y = p1.y + dpp_shr1(p0.y) + dpp_shl1(p2.y);
            unsigned pkv;
            asm("v_cvt_pk_bf16_f32 %0, %1, %2" : "=v"(pkv) : "v"(o.x), "v"(o.y));
            if (jac)
                *(unsigned*)(frq + swz(((i + 1) * PS + (j + 1)) * 128 + pairOff)) = pkv;
        }
    };

    // A/B double-buffered: with the 128-VGPR budget both column sets stay
    // live, so all 68 loads issue before the first consumer wait.
    f32x2 A[19], B[19];
    LOADCOL(A, 0);
    LOADCOL(B, 1);
    __builtin_amdgcn_sched_barrier(0);
    DOSOBEL(A, 0);
    DOSOBEL(B, 1);

    // ---- W fragments + epilogue constants: issue before barrier ----
    bf16x8 wf[18];
#pragma unroll
    for (int i = 0; i < 18; ++i)
        wf[i] = ((const bf16x8*)wt)[i * 64 + lane];

    float b1v[4], w2v[4];
#pragma unroll
    for (int r = 0; r < 4; ++r) {
        int m = 4 * (lane >> 4) + r;
        b1v[r] = b1[m];
        w2v[r] = w2[m];
    }
    const float b2v = b2[0];

    __syncthreads();

    // ---- conv1 via MFMA: wave w handles pixel tiles {w, w+8, w+16} ----
    const int n   = lane & 15;          // pixel within tile (MFMA N)
    const int g16 = (lane >> 4) * 16;   // 8-channel chunk byte offset
    const int DOFF[9] = {0, 1, 2, PS, PS + 1, PS + 2, 2 * PS, 2 * PS + 1, 2 * PS + 2};

#pragma unroll 1
    for (int nt = wave; nt < 19; nt += 8) {
        int p  = nt * 16 + n;
        int pv = p > 288 ? 288 : p;     // clamp dead lanes of last tile
        int pi = pv / 17, pj = pv - pi * 17;
        int base = (pi * PS + pj) * 128 + g16;

        f32x4 acc = {0.f, 0.f, 0.f, 0.f};
#pragma unroll
        for (int d = 0; d < 9; ++d) {
            int off = base + DOFF[d] * 128;
            bf16x8 bfA = *(const bf16x8*)(frq + swz(off));
            bf16x8 bfB = *(const bf16x8*)(frq + swz(off + 64));
            acc = __builtin_amdgcn_mfma_f32_16x16x32_bf16(wf[2 * d],     bfA, acc, 0, 0, 0);
            acc = __builtin_amdgcn_mfma_f32_16x16x32_bf16(wf[2 * d + 1], bfB, acc, 0, 0, 0);
        }

        float part = 0.f;
#pragma unroll
        for (int r = 0; r < 4; ++r)
            part = fmaf(w2v[r], fmaxf(acc[r] + b1v[r], 0.f), part);
        part += __shfl_xor(part, 16);
        part += __shfl_xor(part, 32);

        if (lane < 16 && p < 289) {
            float pre = part + b2v;
            float s = 1.f / (1.f + expf(-pre));
            s = fminf(fmaxf(s, 0.05f), 0.95f);
            out[((size_t)(b * 510 + h0 + pi)) * 510 + (w0 + pj)] = s;
        }
    }
}

extern "C" void kernel_launch(void* const* d_in, const int* in_sizes, int n_in,
                              void* d_out, int out_size, void* d_ws, size_t ws_size,
                              hipStream_t stream) {
    const float* x       = (const float*)d_in[0];
    const float* sobel_w = (const float*)d_in[1];
    const float* w1      = (const float*)d_in[2];
    const float* b1      = (const float*)d_in[3];
    const float* w2      = (const float*)d_in[4];
    const float* b2      = (const float*)d_in[5];
    float* out = (float*)d_out;
    unsigned short* wtab = (unsigned short*)d_ws;   // 18*64*16 = 18432 B

    prep_w1<<<dim3(18), dim3(64), 0, stream>>>(w1, wtab);
    fasa_mfma<<<dim3(3600), dim3(NT), 0, stream>>>(x, sobel_w, wtab, b1, w2, b2, out);
}

// Round 10
// 90.554 us; speedup vs baseline: 11.7470x; 1.0154x over previous
//
#include <hip/hip_runtime.h>

// FrequencyAwareSpatialAttention via MFMA, packed-fp32 sobel, DPP shifts,
// wave-uniform sobel weights, XCD-chunked block swizzle.
// KEY CHANGE (R10): staging loads are inline-asm global_load_dword clusters
// with counted s_waitcnt — the compiler refuses to keep >~4 loads in flight
// (R8: sched_barrier no-op; R9: LDS-pad no-op; VGPR pinned at 52), so the
// 68-load window read was running at depth ~2 => 0.9 TB/s latency-bound.
// Forced "+v" destinations + asm vmcnt(34)/vmcnt(0) guarantee full depth.
// Per block (one 17x17 window, 8 waves):
//   staging: lane = (pair_group, column j); 68 asm dword loads (2ch x 2q x 17
//   rows), sobel in regs, DPP wave_shr/shl horizontal combine,
//   v_cvt_pk_bf16_f32 pack, write frq[pp][c] (swizzled).
//   conv 64->16 3x3 (pad 1): 9 offsets x 2 mfma_f32_16x16x32_bf16, K=64
//   + b1, relu, 1x1 conv 16->1 + b2, sigmoid, clip, scatter.

#define WSZ 17
#define PS  19            // padded 17+2
#define PSS (PS * PS)     // 361
#define NT  512           // 8 waves
#define CH  (510 * 510)   // floats per channel plane

typedef __attribute__((ext_vector_type(8))) short bf16x8;
typedef __attribute__((ext_vector_type(4))) float f32x4;
typedef __attribute__((ext_vector_type(2))) float f32x2;

// XOR swizzle: involution within each 128B frq row (row = padded pixel).
__device__ __forceinline__ int swz(int off) {
    return off ^ (((off >> 7) & 7) << 4);
}

__device__ __forceinline__ unsigned short f2bf(float f) {
    union { float f; unsigned u; } v; v.f = f;
    unsigned u = v.u;
    unsigned r = u + 0x7fffu + ((u >> 16) & 1u);   // RNE
    return (unsigned short)(r >> 16);
}

// lane i <- lane i-1 (wave_shr:1), lane 0 <- 0
__device__ __forceinline__ float dpp_shr1(float v) {
    return __int_as_float(
        __builtin_amdgcn_update_dpp(0, __float_as_int(v), 0x138, 0xf, 0xf, true));
}
// lane i <- lane i+1 (wave_shl:1), lane 63 <- 0
__device__ __forceinline__ float dpp_shl1(float v) {
    return __int_as_float(
        __builtin_amdgcn_update_dpp(0, __float_as_int(v), 0x130, 0xf, 0xf, true));
}

// 8 forced-depth loads: rows 2k,2k+1 at voff k via offset:0/2040 immediates.
#define GLD8(d0,d1,d2,d3,d4,d5,d6,d7, o0,o1,o2,o3, sp)      \
    asm volatile(                                            \
        "global_load_dword %0, %8, %12\n\t"                  \
        "global_load_dword %1, %8, %12 offset:2040\n\t"      \
        "global_load_dword %2, %9, %12\n\t"                  \
        "global_load_dword %3, %9, %12 offset:2040\n\t"      \
        "global_load_dword %4, %10, %12\n\t"                 \
        "global_load_dword %5, %10, %12 offset:2040\n\t"     \
        "global_load_dword %6, %11, %12\n\t"                 \
        "global_load_dword %7, %11, %12 offset:2040\n\t"     \
        : "+v"(d0),"+v"(d1),"+v"(d2),"+v"(d3),               \
          "+v"(d4),"+v"(d5),"+v"(d6),"+v"(d7)                \
        : "v"(o0),"v"(o1),"v"(o2),"v"(o3),"s"(sp))

// 9 loads: rows 8..15 (pairs) + row 16.
#define GLD9(d0,d1,d2,d3,d4,d5,d6,d7,d8, o0,o1,o2,o3,o4, sp) \
    asm volatile(                                            \
        "global_load_dword %0, %9, %14\n\t"                  \
        "global_load_dword %1, %9, %14 offset:2040\n\t"      \
        "global_load_dword %2, %10, %14\n\t"                 \
        "global_load_dword %3, %10, %14 offset:2040\n\t"     \
        "global_load_dword %4, %11, %14\n\t"                 \
        "global_load_dword %5, %11, %14 offset:2040\n\t"     \
        "global_load_dword %6, %12, %14\n\t"                 \
        "global_load_dword %7, %12, %14 offset:2040\n\t"     \
        "global_load_dword %8, %13, %14\n\t"                 \
        : "+v"(d0),"+v"(d1),"+v"(d2),"+v"(d3),"+v"(d4),      \
          "+v"(d5),"+v"(d6),"+v"(d7),"+v"(d8)                \
        : "v"(o0),"v"(o1),"v"(o2),"v"(o3),"v"(o4),"s"(sp))

// Pre-kernel: transpose+convert w1 [16][64][3][3] fp32 into A-fragment order.
// Fragment (dij, ks): lane l holds A[m = l&15][k = ks*32 + 8*(l>>4) + j], j=0..7.
__global__ void prep_w1(const float* __restrict__ w1, unsigned short* __restrict__ wt) {
    const int dij = blockIdx.x >> 1;
    const int ks  = blockIdx.x & 1;
    const int l   = threadIdx.x;           // 0..63
    const int m   = l & 15;
    const int kb  = ks * 32 + 8 * (l >> 4);
    bf16x8 v;
#pragma unroll
    for (int jj = 0; jj < 8; ++jj)
        v[jj] = (short)f2bf(w1[m * 576 + (kb + jj) * 9 + dij]);
    ((bf16x8*)wt)[blockIdx.x * 64 + l] = v;
}

__global__ __launch_bounds__(NT, 4)
void fasa_mfma(const float* __restrict__ x,
               const float* __restrict__ sobel_w,
               const unsigned short* __restrict__ wt,
               const float* __restrict__ b1,
               const float* __restrict__ w2,
               const float* __restrict__ b2,
               float* __restrict__ out)
{
    __shared__ __align__(16) char frq[PSS * 128];   // 46.2 KB, [pp][c] bf16 swizzled

    const int t    = threadIdx.x;
    const int lane = t & 63;
    const int wave = __builtin_amdgcn_readfirstlane(t >> 6);

    // XCD-chunked swizzle: HW maps bid%8 -> XCD; each XCD gets a contiguous
    // run of 450 windows (15 window-rows). 3600 = 8*450 (bijective).
    const int bid = blockIdx.x;
    const int win = (bid & 7) * 450 + (bid >> 3);   // b*900 + wh*30 + ww
    const int b   = win / 900;
    const int rem = win % 900;
    const int h0  = (rem / 30) * WSZ;
    const int w0  = (rem % 30) * WSZ;

    // ---- zero the 72 border rows of frq (interior rows all get written) ----
    for (int u = t; u < 72 * 8; u += NT) {
        int r = u >> 3, k = u & 7;
        int row;
        if      (r < 19) row = r;                   // pi == 0
        else if (r < 38) row = 342 + (r - 19);      // pi == 18
        else if (r < 55) row = (r - 37) * PS;       // pj == 0, pi 1..17
        else             row = (r - 54) * PS + 18;  // pj == 18, pi 1..17
        *(f32x4*)(frq + row * 128 + k * 16) = (f32x4){0.f, 0.f, 0.f, 0.f};
    }

    // ---- sobel weights: ALL channels share one 3x3 (tiled in setup) ----
    float sw[9];
#pragma unroll
    for (int k = 0; k < 9; ++k) sw[k] = sobel_w[k];

    // ---- staging: lane = (grp, j); pair = 2*wave + grp + 16*q, q = 0,1 ----
    const int j   = lane & 31;       // column, active when j < 17
    const int grp = lane >> 5;       // which pair of this wave's two
    const bool jac = (j < 17);

    // wave-uniform bases: channel 4*wave, then q/y offsets folded into saddr
    const float* sp00 = x + ((size_t)(b * 64 + 4 * wave)) * CH
                          + (size_t)h0 * 510 + w0;
    const float* sp01 = sp00 + (size_t)CH;        // +1 channel (y of pair)
    const float* sp10 = sp00 + (size_t)32 * CH;   // q=1
    const float* sp11 = sp10 + (size_t)CH;

    // per-lane voffsets: channel-pair offset + column + row pairs (4080*k)
    const unsigned v0 = (unsigned)((grp * 2 * CH + j) * 4);
    const unsigned vk0 = v0,           vk1 = v0 + 4080u,  vk2 = v0 + 8160u;
    const unsigned vk3 = v0 + 12240u,  vk4 = v0 + 16320u, vk5 = v0 + 20400u;
    const unsigned vk6 = v0 + 24480u,  vk7 = v0 + 28560u, vk8 = v0 + 32640u;

    // data regs, pre-zeroed at full exec so inactive lanes (j>=17) keep the
    // zero columns the DPP edge handling relies on (lanes 17/31/49/63).
    float xA[17], yA[17], xB[17], yB[17];
#pragma unroll
    for (int i = 0; i < 17; ++i) { xA[i] = 0.f; yA[i] = 0.f; xB[i] = 0.f; yB[i] = 0.f; }

    if (jac) {
        GLD8(xA[0],xA[1],xA[2],xA[3],xA[4],xA[5],xA[6],xA[7], vk0,vk1,vk2,vk3, sp00);
        GLD9(xA[8],xA[9],xA[10],xA[11],xA[12],xA[13],xA[14],xA[15],xA[16],
             vk4,vk5,vk6,vk7,vk8, sp00);
        GLD8(yA[0],yA[1],yA[2],yA[3],yA[4],yA[5],yA[6],yA[7], vk0,vk1,vk2,vk3, sp01);
        GLD9(yA[8],yA[9],yA[10],yA[11],yA[12],yA[13],yA[14],yA[15],yA[16],
             vk4,vk5,vk6,vk7,vk8, sp01);
        GLD8(xB[0],xB[1],xB[2],xB[3],xB[4],xB[5],xB[6],xB[7], vk0,vk1,vk2,vk3, sp10);
        GLD9(xB[8],xB[9],xB[10],xB[11],xB[12],xB[13],xB[14],xB[15],xB[16],
             vk4,vk5,vk6,vk7,vk8, sp10);
        GLD8(yB[0],yB[1],yB[2],yB[3],yB[4],yB[5],yB[6],yB[7], vk0,vk1,vk2,vk3, sp11);
        GLD9(yB[8],yB[9],yB[10],yB[11],yB[12],yB[13],yB[14],yB[15],yB[16],
             vk4,vk5,vk6,vk7,vk8, sp11);
    }

    auto DOSOBEL = [&](const float* xr, const float* yr, int q) {
        const int pr = 2 * wave + grp + 16 * q;       // pair index 0..31
        const int pairOff = pr * 4;                   // pair byte offset in frq row
#pragma unroll
        for (int i = 0; i < 17; ++i) {
            f32x2 top = { (i > 0  ? xr[i - 1] : 0.f), (i > 0  ? yr[i - 1] : 0.f) };
            f32x2 mid = { xr[i],                       yr[i] };
            f32x2 bot = { (i < 16 ? xr[i + 1] : 0.f), (i < 16 ? yr[i + 1] : 0.f) };
            f32x2 p0 = sw[0] * top + sw[3] * mid + sw[6] * bot;
            f32x2 p1 = sw[1] * top + sw[4] * mid + sw[7] * bot;
            f32x2 p2 = sw[2] * top + sw[5] * mid + sw[8] * bot;
            // o(j) = p0(j-1) + p1(j) + p2(j+1); zero cols at j>=17 supply pads
            f32x2 o;
            o.x = p1.x + dpp_shr1(p0.x) + dpp_shl1(p2.x);
            o.y = p1.y + dpp_shr1(p0.y) + dpp_shl1(p2.y);
            unsigned pkv;
            asm("v_cvt_pk_bf16_f32 %0, %1, %2" : "=v"(pkv) : "v"(o.x), "v"(o.y));
            if (jac)
                *(unsigned*)(frq + swz(((i + 1) * PS + (j + 1)) * 128 + pairOff)) = pkv;
        }
    };

    // A ready (B's 34 still in flight under sobel A), then drain for B.
    asm volatile("s_waitcnt vmcnt(34)" ::: "memory");
    __builtin_amdgcn_sched_barrier(0);
    DOSOBEL(xA, yA, 0);
    asm volatile("s_waitcnt vmcnt(0)" ::: "memory");
    __builtin_amdgcn_sched_barrier(0);
    DOSOBEL(xB, yB, 1);

    // ---- W fragments + epilogue constants: issue before barrier ----
    bf16x8 wf[18];
#pragma unroll
    for (int i = 0; i < 18; ++i)
        wf[i] = ((const bf16x8*)wt)[i * 64 + lane];

    float b1v[4], w2v[4];
#pragma unroll
    for (int r = 0; r < 4; ++r) {
        int m = 4 * (lane >> 4) + r;
        b1v[r] = b1[m];
        w2v[r] = w2[m];
    }
    const float b2v = b2[0];

    __syncthreads();

    // ---- conv1 via MFMA: wave w handles pixel tiles {w, w+8, w+16} ----
    const int n   = lane & 15;          // pixel within tile (MFMA N)
    const int g16 = (lane >> 4) * 16;   // 8-channel chunk byte offset
    const int DOFF[9] = {0, 1, 2, PS, PS + 1, PS + 2, 2 * PS, 2 * PS + 1, 2 * PS + 2};

#pragma unroll 1
    for (int nt = wave; nt < 19; nt += 8) {
        int p  = nt * 16 + n;
        int pv = p > 288 ? 288 : p;     // clamp dead lanes of last tile
        int pi = pv / 17, pj = pv - pi * 17;
        int base = (pi * PS + pj) * 128 + g16;

        f32x4 acc = {0.f, 0.f, 0.f, 0.f};
#pragma unroll
        for (int d = 0; d < 9; ++d) {
            int off = base + DOFF[d] * 128;
            bf16x8 bfA = *(const bf16x8*)(frq + swz(off));
            bf16x8 bfB = *(const bf16x8*)(frq + swz(off + 64));
            acc = __builtin_amdgcn_mfma_f32_16x16x32_bf16(wf[2 * d],     bfA, acc, 0, 0, 0);
            acc = __builtin_amdgcn_mfma_f32_16x16x32_bf16(wf[2 * d + 1], bfB, acc, 0, 0, 0);
        }

        float part = 0.f;
#pragma unroll
        for (int r = 0; r < 4; ++r)
            part = fmaf(w2v[r], fmaxf(acc[r] + b1v[r], 0.f), part);
        part += __shfl_xor(part, 16);
        part += __shfl_xor(part, 32);

        if (lane < 16 && p < 289) {
            float pre = part + b2v;
            float s = 1.f / (1.f + expf(-pre));
            s = fminf(fmaxf(s, 0.05f), 0.95f);
            out[((size_t)(b * 510 + h0 + pi)) * 510 + (w0 + pj)] = s;
        }
    }
}

extern "C" void kernel_launch(void* const* d_in, const int* in_sizes, int n_in,
                              void* d_out, int out_size, void* d_ws, size_t ws_size,
                              hipStream_t stream) {
    const float* x       = (const float*)d_in[0];
    const float* sobel_w = (const float*)d_in[1];
    const float* w1      = (const float*)d_in[2];
    const float* b1      = (const float*)d_in[3];
    const float* w2      = (const float*)d_in[4];
    const float* b2      = (const float*)d_in[5];
    float* out = (float*)d_out;
    unsigned short* wtab = (unsigned short*)d_ws;   // 18*64*16 = 18432 B

    prep_w1<<<dim3(18), dim3(64), 0, stream>>>(w1, wtab);
    fasa_mfma<<<dim3(3600), dim3(NT), 0, stream>>>(x, sobel_w, wtab, b1, w2, b2, out);
}